// Round 2
// baseline (4503.183 us; speedup 1.0000x reference)
//
#include <hip/hip_runtime.h>
#include <cmath>

// RWKV7 time-mixing, B=4 L=2048 D=1024 H=16 Dh=64. Inputs/outputs fp32; internal bf16 MFMA.
// Pipeline: convert-weights -> mix -> [r,k,v,lora1x4] GEMMs -> [lora2x4] GEMMs -> prep -> scan -> gnorm -> out GEMM.

#define DEV __device__ __forceinline__

typedef unsigned short u16;
typedef unsigned int u32;
typedef __bf16 bf16x8 __attribute__((ext_vector_type(8)));
typedef float f32x4 __attribute__((ext_vector_type(4)));

constexpr int Bx = 4, Lx = 2048, Dx = 1024, Hx = 16, Dh = 64;
constexpr int NTOK = Bx * Lx;       // 8192
constexpr float EPS_GN = 0.00064f;

DEV float bf2f(u16 u) { union { u32 i; float f; } c; c.i = ((u32)u) << 16; return c.f; }
DEV u16 f2bf(float f) {
    union { float f; u32 i; } c; c.f = f;
    u32 r = c.i + 0x7FFFu + ((c.i >> 16) & 1u);
    return (u16)(r >> 16);
}

// ---------------- weight f32 -> bf16 conversion (12 tensors, one dispatch) ----------------
__global__ __launch_bounds__(256) void conv_kernel(
    const float* s0, const float* s1, const float* s2, const float* s3,
    const float* s4, const float* s5, const float* s6, const float* s7,
    const float* s8, const float* s9, const float* s10, const float* s11,
    u16* d0, u16* d1, u16* d2, u16* d3, u16* d4, u16* d5,
    u16* d6, u16* d7, u16* d8, u16* d9, u16* d10, u16* d11)
{
    const float* srcs[12] = {s0,s1,s2,s3,s4,s5,s6,s7,s8,s9,s10,s11};
    u16* dsts[12] = {d0,d1,d2,d3,d4,d5,d6,d7,d8,d9,d10,d11};
    const int ns[12] = {1048576,1048576,1048576,1048576,65536,65536,32768,32768,65536,65536,131072,131072};
    int t = blockIdx.y;
    int i = (blockIdx.x * 256 + threadIdx.x) * 4;
    if (i >= ns[t]) return;
    float4 v = *(const float4*)(srcs[t] + i);
    ushort4 o;
    o.x = f2bf(v.x); o.y = f2bf(v.y); o.z = f2bf(v.z); o.w = f2bf(v.w);
    *(ushort4*)(dsts[t] + i) = o;
}

// ---------------- token-shift mix: out_t = bf16(x + (x_prev - x) * mix_t) ----------------
__global__ __launch_bounds__(256) void mix_kernel(
    const float* __restrict__ x,
    const float* __restrict__ mr, const float* __restrict__ mw, const float* __restrict__ mk,
    const float* __restrict__ mv, const float* __restrict__ ma, const float* __restrict__ mg,
    u16* __restrict__ XR, u16* __restrict__ XW, u16* __restrict__ XK,
    u16* __restrict__ XV, u16* __restrict__ XA, u16* __restrict__ XG)
{
    int gi = blockIdx.x * 256 + threadIdx.x;     // 0 .. NTOK*Dx/4-1
    int n  = gi >> 8;                            // token
    int d4 = (gi & 255) << 2;                    // channel group of 4
    int l  = n & (Lx - 1);
    size_t o = (size_t)n * Dx + d4;
    float4 xc = *(const float4*)(x + o);
    float4 xp = make_float4(0.f, 0.f, 0.f, 0.f);
    if (l != 0) xp = *(const float4*)(x + o - Dx);
    float dx0 = xp.x - xc.x, dx1 = xp.y - xc.y, dx2 = xp.z - xc.z, dx3 = xp.w - xc.w;
    const float* mvs[6] = {mr, mw, mk, mv, ma, mg};
    u16* dsts[6] = {XR, XW, XK, XV, XA, XG};
#pragma unroll
    for (int j = 0; j < 6; ++j) {
        float4 m = *(const float4*)(mvs[j] + d4);
        ushort4 r;
        r.x = f2bf(fmaf(dx0, m.x, xc.x));
        r.y = f2bf(fmaf(dx1, m.y, xc.y));
        r.z = f2bf(fmaf(dx2, m.z, xc.z));
        r.w = f2bf(fmaf(dx3, m.w, xc.w));
        *(ushort4*)(dsts[j] + o) = r;
    }
}

// ---------------- bf16 MFMA GEMM, C[M,N] = act(A[M,K] . B[N,K]^T + bias_f32) ----------------
// ACT: 0 none, 1 sigmoid, 2 tanh, 3 exp(-0.606531*sigmoid)
template <int BN, int ACT, bool BIAS, bool F32OUT>
__global__ __launch_bounds__(256) void gemm_nt(
    const u16* __restrict__ A, const u16* __restrict__ Bm,
    const float* __restrict__ bias, void* __restrict__ Cv,
    int M, int N, int K)
{
    constexpr int BM = 128, BK = 32;
    constexpr int LDT = BK + 8;                    // +8 ushort pad: 80B rows, keeps 16B align
    constexpr int WGM = (BN == 128) ? 2 : 4;
    constexpr int WGN = (BN == 128) ? 2 : 1;
    constexpr int WTM = BM / WGM, WTN = BN / WGN;
    constexpr int ITM = WTM / 16, ITN = WTN / 16;
    __shared__ __align__(16) u16 Asm[BM * LDT];
    __shared__ __align__(16) u16 Bsm[BN * LDT];
    const int tid = threadIdx.x;
    const int wid = tid >> 6, lane = tid & 63;
    const int q = lane >> 4, r16 = lane & 15;
    const size_t m0 = (size_t)blockIdx.x * BM;
    const size_t n0 = (size_t)blockIdx.y * BN;
    const int wm = (wid % WGM) * WTM;
    const int wn = (wid / WGM) * WTN;
    f32x4 acc[ITM][ITN];
    const f32x4 zf = {0.f, 0.f, 0.f, 0.f};
#pragma unroll
    for (int i = 0; i < ITM; ++i)
#pragma unroll
        for (int j = 0; j < ITN; ++j) acc[i][j] = zf;

    for (int k0 = 0; k0 < K; k0 += BK) {
#pragma unroll
        for (int it = 0; it < (BM * BK) / 2048; ++it) {
            int pp = tid * 8 + it * 2048;
            int row = pp >> 5, col = pp & 31;
            *(uint4*)&Asm[row * LDT + col] = *(const uint4*)(A + (m0 + row) * K + k0 + col);
        }
        if constexpr (BN * BK >= 2048) {
#pragma unroll
            for (int it = 0; it < (BN * BK) / 2048; ++it) {
                int pp = tid * 8 + it * 2048;
                int row = pp >> 5, col = pp & 31;
                *(uint4*)&Bsm[row * LDT + col] = *(const uint4*)(Bm + (n0 + row) * K + k0 + col);
            }
        } else {
            int pp = tid * 8;
            if (pp < BN * BK) {
                int row = pp >> 5, col = pp & 31;
                *(uint4*)&Bsm[row * LDT + col] = *(const uint4*)(Bm + (n0 + row) * K + k0 + col);
            }
        }
        __syncthreads();
        bf16x8 af[ITM], bfr[ITN];
#pragma unroll
        for (int im = 0; im < ITM; ++im)
            af[im] = *(const bf16x8*)&Asm[(wm + im * 16 + r16) * LDT + q * 8];
#pragma unroll
        for (int in = 0; in < ITN; ++in)
            bfr[in] = *(const bf16x8*)&Bsm[(wn + in * 16 + r16) * LDT + q * 8];
#pragma unroll
        for (int im = 0; im < ITM; ++im)
#pragma unroll
            for (int in = 0; in < ITN; ++in)
                acc[im][in] = __builtin_amdgcn_mfma_f32_16x16x32_bf16(af[im], bfr[in], acc[im][in], 0, 0, 0);
        __syncthreads();
    }
    // epilogue: C/D layout col = lane&15 (n), row = quad*4+reg (m)  [m89-verified]
#pragma unroll
    for (int im = 0; im < ITM; ++im) {
#pragma unroll
        for (int in = 0; in < ITN; ++in) {
#pragma unroll
            for (int e = 0; e < 4; ++e) {
                size_t row = m0 + wm + im * 16 + q * 4 + e;
                size_t col = n0 + wn + in * 16 + r16;
                float val = acc[im][in][e];
                if constexpr (BIAS) val += bias[col];
                if constexpr (ACT == 1) val = 1.f / (1.f + __expf(-val));
                else if constexpr (ACT == 2) val = tanhf(val);
                else if constexpr (ACT == 3) val = __expf(-0.606531f / (1.f + __expf(-val)));
                if constexpr (F32OUT) ((float*)Cv)[row * (size_t)N + col] = val;
                else ((u16*)Cv)[row * (size_t)N + col] = f2bf(val);
            }
        }
    }
}

// ---------------- prep: kk-normalize, a/b vectors, k/v updates ----------------
__global__ __launch_bounds__(256) void prep_kernel(
    u16* __restrict__ Kb, u16* __restrict__ Vb,
    const u16* __restrict__ ICLR, const u16* __restrict__ VVb, const float* __restrict__ vfirst,
    const float* __restrict__ k_k, const float* __restrict__ k_a,
    u16* __restrict__ Av, u16* __restrict__ Bv)
{
    int g = blockIdx.x * 4 + (threadIdx.x >> 6);   // (token,head) pair
    int lane = threadIdx.x & 63;
    int h = g & (Hx - 1);
    size_t idx = (size_t)g * 64 + lane;            // == n*1024 + h*64 + lane
    int hd = h * 64 + lane;
    float k = bf2f(Kb[idx]);
    float iclr = bf2f(ICLR[idx]);
    float kkn = k * k_k[hd];
    float s = kkn * kkn;
#pragma unroll
    for (int off = 32; off > 0; off >>= 1) s += __shfl_xor(s, off, 64);
    float nrm = fmaxf(sqrtf(s), 1e-7f);
    float kk = kkn / nrm;
    Av[idx] = f2bf(-kk);
    Bv[idx] = f2bf(kk * iclr);
    Kb[idx] = f2bf(k * (1.f + (iclr - 1.f) * k_a[hd]));
    float v = bf2f(Vb[idx]), vv = bf2f(VVb[idx]), vf = vfirst[idx];
    Vb[idx] = f2bf(fmaf(vf - v, vv, v));
}

// ---------------- WKV7 scan: one wave per (b,h), thread-per-row, state in regs ----------------
__global__ __launch_bounds__(64) void scan_kernel(
    const u16* __restrict__ Rb, const float* __restrict__ Wd,
    const u16* __restrict__ Kb, const u16* __restrict__ Vb,
    const u16* __restrict__ Av, const u16* __restrict__ Bv,
    float* __restrict__ Y)
{
    const int bh = blockIdx.x;                    // b*16+h
    const int lane = threadIdx.x;                 // row i
    const size_t base = (size_t)(bh >> 4) * ((size_t)Lx * Dx) + (size_t)(bh & 15) * 64 + lane;
    __shared__ __align__(16) float shr[64], shw[64], shk[64], sha[64], shb[64];
    float S[64];
#pragma unroll
    for (int j = 0; j < 64; ++j) S[j] = 0.f;
    float pr = bf2f(Rb[base]);
    float pw = Wd[base];
    float pk = bf2f(Kb[base]);
    float pa = bf2f(Av[base]);
    float pb = bf2f(Bv[base]);
    float pv = bf2f(Vb[base]);
    for (int t = 0; t < Lx; ++t) {
        shr[lane] = pr; shw[lane] = pw; shk[lane] = pk; sha[lane] = pa; shb[lane] = pb;
        const float v = pv;
        __syncthreads();
        if (t + 1 < Lx) {                         // prefetch next step, overlaps compute
            size_t nb = base + (size_t)(t + 1) * Dx;
            pr = bf2f(Rb[nb]); pw = Wd[nb]; pk = bf2f(Kb[nb]);
            pa = bf2f(Av[nb]); pb = bf2f(Bv[nb]); pv = bf2f(Vb[nb]);
        }
        float sa0 = 0.f, sa1 = 0.f, sa2 = 0.f, sa3 = 0.f;
#pragma unroll
        for (int gq = 0; gq < 16; ++gq) {
            float4 a4 = ((const float4*)sha)[gq];
            sa0 = fmaf(S[4 * gq + 0], a4.x, sa0);
            sa1 = fmaf(S[4 * gq + 1], a4.y, sa1);
            sa2 = fmaf(S[4 * gq + 2], a4.z, sa2);
            sa3 = fmaf(S[4 * gq + 3], a4.w, sa3);
        }
        const float sa = (sa0 + sa1) + (sa2 + sa3);
        float y0 = 0.f, y1 = 0.f, y2 = 0.f, y3 = 0.f;
#pragma unroll
        for (int gq = 0; gq < 16; ++gq) {
            float4 w4 = ((const float4*)shw)[gq];
            float4 k4 = ((const float4*)shk)[gq];
            float4 b4 = ((const float4*)shb)[gq];
            float4 r4 = ((const float4*)shr)[gq];
            float s;
            s = fmaf(S[4 * gq + 0], w4.x, fmaf(v, k4.x, sa * b4.x)); S[4 * gq + 0] = s; y0 = fmaf(s, r4.x, y0);
            s = fmaf(S[4 * gq + 1], w4.y, fmaf(v, k4.y, sa * b4.y)); S[4 * gq + 1] = s; y1 = fmaf(s, r4.y, y1);
            s = fmaf(S[4 * gq + 2], w4.z, fmaf(v, k4.z, sa * b4.z)); S[4 * gq + 2] = s; y2 = fmaf(s, r4.z, y2);
            s = fmaf(S[4 * gq + 3], w4.w, fmaf(v, k4.w, sa * b4.w)); S[4 * gq + 3] = s; y3 = fmaf(s, r4.w, y3);
        }
        Y[base + (size_t)t * Dx] = (y0 + y1) + (y2 + y3);
        __syncthreads();
    }
}

// ---------------- group-norm + rkr residual + gate (OG written in-place over GATE) ----------------
__global__ __launch_bounds__(256) void gnorm_kernel(
    const float* __restrict__ Y, const u16* __restrict__ Rb, const u16* __restrict__ Kb,
    const u16* __restrict__ Vb, const float* __restrict__ r_k,
    const float* __restrict__ gnw, const float* __restrict__ gnb,
    u16* __restrict__ GATE_OG)
{
    int g = blockIdx.x * 4 + (threadIdx.x >> 6);
    int lane = threadIdx.x & 63;
    int h = g & (Hx - 1);
    size_t idx = (size_t)g * 64 + lane;
    int hd = h * 64 + lane;
    float y = Y[idx];
    float r = bf2f(Rb[idx]), k = bf2f(Kb[idx]), v = bf2f(Vb[idx]);
    float rkr = r * k * r_k[hd];
    float s1 = y, s2 = y * y, s3 = rkr;
#pragma unroll
    for (int off = 32; off > 0; off >>= 1) {
        s1 += __shfl_xor(s1, off, 64);
        s2 += __shfl_xor(s2, off, 64);
        s3 += __shfl_xor(s3, off, 64);
    }
    float mean = s1 * (1.f / 64.f);
    float var  = s2 * (1.f / 64.f) - mean * mean;
    float inv = 1.f / sqrtf(var + EPS_GN);
    float o = gnw[hd] * ((y - mean) * inv) + gnb[hd];
    o += s3 * v;
    GATE_OG[idx] = f2bf(o * bf2f(GATE_OG[idx]));
}

// ---------------- launch ----------------
extern "C" void kernel_launch(void* const* d_in, const int* in_sizes, int n_in,
                              void* d_out, int out_size, void* d_ws, size_t ws_size,
                              hipStream_t stream)
{
    const float* x      = (const float*)d_in[0];
    const float* vfirst = (const float*)d_in[1];
    const float* x_r = (const float*)d_in[2];
    const float* x_w = (const float*)d_in[3];
    const float* x_k = (const float*)d_in[4];
    const float* x_v = (const float*)d_in[5];
    const float* x_a = (const float*)d_in[6];
    const float* x_g = (const float*)d_in[7];
    const float* k_k = (const float*)d_in[8];
    const float* k_a = (const float*)d_in[9];
    const float* r_k = (const float*)d_in[10];
    const float* Wr  = (const float*)d_in[11];
    const float* Wk  = (const float*)d_in[12];
    const float* Wv  = (const float*)d_in[13];
    const float* Wo  = (const float*)d_in[14];
    const float* gnw = (const float*)d_in[15];
    const float* gnb = (const float*)d_in[16];
    const float* wA  = (const float*)d_in[17];
    const float* wB  = (const float*)d_in[18];
    const float* wb  = (const float*)d_in[19];
    const float* vA  = (const float*)d_in[20];
    const float* vB  = (const float*)d_in[21];
    const float* vb  = (const float*)d_in[22];
    const float* aA  = (const float*)d_in[23];
    const float* aB  = (const float*)d_in[24];
    const float* ab  = (const float*)d_in[25];
    const float* gA  = (const float*)d_in[26];
    const float* gB  = (const float*)d_in[27];

    char* ws = (char*)d_ws;
    const size_t SLOT = (size_t)NTOK * Dx * 2;   // 16 MiB; 14 slots (~224 MiB)
    u16* XR = (u16*)(ws + 0 * SLOT);
    u16* XW = (u16*)(ws + 1 * SLOT);
    u16* XK = (u16*)(ws + 2 * SLOT);
    u16* XV = (u16*)(ws + 3 * SLOT);
    u16* XA = (u16*)(ws + 4 * SLOT);
    u16* XG = (u16*)(ws + 5 * SLOT);
    u16* Rbuf = (u16*)(ws + 6 * SLOT);
    u16* Kbuf = (u16*)(ws + 7 * SLOT);
    u16* Vbuf = (u16*)(ws + 8 * SLOT);
    u16* HW = (u16*)(ws + 9 * SLOT);             // slot 9 holds all 4 lora hiddens
    u16* HA = HW + (size_t)NTOK * 64;
    u16* HV = HA + (size_t)NTOK * 64;
    u16* HG = HV + (size_t)NTOK * 32;
    u16* Bvec = (u16*)(ws + 10 * SLOT);
    float* Yb = (float*)(ws + 11 * SLOT);        // slots 11-12 (fp32)
    // slot 13: converted bf16 weights (~9.2 MiB used)
    u16* WrB = (u16*)(ws + 13 * SLOT);
    u16* WkB = WrB + 1048576;
    u16* WvB = WkB + 1048576;
    u16* WoB = WvB + 1048576;
    u16* wAB = WoB + 1048576;
    u16* wBB = wAB + 65536;
    u16* vAB = wBB + 65536;
    u16* vBB = vAB + 32768;
    u16* aAB = vBB + 32768;
    u16* aBB = aAB + 65536;
    u16* gAB = aBB + 65536;
    u16* gBB = gAB + 131072;
    // reuse of consumed mix slots:
    float* Wdec = (float*)(ws + 0 * SLOT);       // slots 0-1 (fp32 decay)
    u16* ICLR = (u16*)(ws + 2 * SLOT);
    u16* VVb  = (u16*)(ws + 3 * SLOT);
    u16* GATE = (u16*)(ws + 4 * SLOT);           // gnorm writes OG in-place here
    u16* Avec = (u16*)(ws + 5 * SLOT);

    dim3 blk(256);
    conv_kernel<<<dim3(1024, 12), blk, 0, stream>>>(Wr, Wk, Wv, Wo, wA, wB, vA, vB, aA, aB, gA, gB,
                                                    WrB, WkB, WvB, WoB, wAB, wBB, vAB, vBB, aAB, aBB, gAB, gBB);
    mix_kernel<<<(NTOK * Dx / 4) / 256, blk, 0, stream>>>(x, x_r, x_w, x_k, x_v, x_a, x_g,
                                                          XR, XW, XK, XV, XA, XG);
    // big projections
    gemm_nt<128, 0, false, false><<<dim3(64, 8), blk, 0, stream>>>(XR, WrB, nullptr, Rbuf, NTOK, 1024, 1024);
    gemm_nt<128, 0, false, false><<<dim3(64, 8), blk, 0, stream>>>(XK, WkB, nullptr, Kbuf, NTOK, 1024, 1024);
    gemm_nt<128, 0, false, false><<<dim3(64, 8), blk, 0, stream>>>(XV, WvB, nullptr, Vbuf, NTOK, 1024, 1024);
    // lora stage 1 (down-proj)
    gemm_nt<64, 2, false, false><<<dim3(64, 1), blk, 0, stream>>>(XW, wAB, nullptr, HW, NTOK, 64, 1024);
    gemm_nt<64, 0, false, false><<<dim3(64, 1), blk, 0, stream>>>(XA, aAB, nullptr, HA, NTOK, 64, 1024);
    gemm_nt<32, 0, false, false><<<dim3(64, 1), blk, 0, stream>>>(XV, vAB, nullptr, HV, NTOK, 32, 1024);
    gemm_nt<128, 1, false, false><<<dim3(64, 1), blk, 0, stream>>>(XG, gAB, nullptr, HG, NTOK, 128, 1024);
    // lora stage 2 (up-proj, fused epilogues); mix slots now free for reuse
    gemm_nt<128, 3, true,  true ><<<dim3(64, 8), blk, 0, stream>>>(HW, wBB, wb, Wdec, NTOK, 1024, 64);
    gemm_nt<128, 1, true,  false><<<dim3(64, 8), blk, 0, stream>>>(HA, aBB, ab, ICLR, NTOK, 1024, 64);
    gemm_nt<128, 1, true,  false><<<dim3(64, 8), blk, 0, stream>>>(HV, vBB, vb, VVb, NTOK, 1024, 32);
    gemm_nt<128, 0, false, false><<<dim3(64, 8), blk, 0, stream>>>(HG, gBB, nullptr, GATE, NTOK, 1024, 128);

    prep_kernel<<<(NTOK * Hx) / 4, blk, 0, stream>>>(Kbuf, Vbuf, ICLR, VVb, vfirst, k_k, k_a, Avec, Bvec);
    scan_kernel<<<Bx * Hx, 64, 0, stream>>>(Rbuf, Wdec, Kbuf, Vbuf, Avec, Bvec, Yb);
    gnorm_kernel<<<(NTOK * Hx) / 4, blk, 0, stream>>>(Yb, Rbuf, Kbuf, Vbuf, r_k, gnw, gnb, GATE);
    gemm_nt<128, 0, false, true><<<dim3(64, 8), blk, 0, stream>>>(GATE, WoB, nullptr, d_out, NTOK, 1024, 1024);
}

// Round 3
// 1997.231 us; speedup vs baseline: 2.2547x; 2.2547x over previous
//
#include <hip/hip_runtime.h>
#include <cmath>

// RWKV7 time-mixing, B=4 L=2048 D=1024 H=16 Dh=64. Inputs/outputs fp32; internal bf16 MFMA.
// Pipeline: convert-weights -> mix -> [r,k,v,lora1x4] GEMMs -> [lora2x4] GEMMs -> prep -> scan -> gnorm -> out GEMM.

#define DEV __device__ __forceinline__

typedef unsigned short u16;
typedef unsigned int u32;
typedef __bf16 bf16x8 __attribute__((ext_vector_type(8)));
typedef float f32x4 __attribute__((ext_vector_type(4)));

constexpr int Bx = 4, Lx = 2048, Dx = 1024, Hx = 16, Dh = 64;
constexpr int NTOK = Bx * Lx;       // 8192
constexpr float EPS_GN = 0.00064f;

DEV float bf2f(u16 u) { union { u32 i; float f; } c; c.i = ((u32)u) << 16; return c.f; }
DEV u16 f2bf(float f) {
    union { float f; u32 i; } c; c.f = f;
    u32 r = c.i + 0x7FFFu + ((c.i >> 16) & 1u);
    return (u16)(r >> 16);
}

// ---------------- weight f32 -> bf16 conversion (12 tensors, one dispatch) ----------------
__global__ __launch_bounds__(256) void conv_kernel(
    const float* s0, const float* s1, const float* s2, const float* s3,
    const float* s4, const float* s5, const float* s6, const float* s7,
    const float* s8, const float* s9, const float* s10, const float* s11,
    u16* d0, u16* d1, u16* d2, u16* d3, u16* d4, u16* d5,
    u16* d6, u16* d7, u16* d8, u16* d9, u16* d10, u16* d11)
{
    const float* srcs[12] = {s0,s1,s2,s3,s4,s5,s6,s7,s8,s9,s10,s11};
    u16* dsts[12] = {d0,d1,d2,d3,d4,d5,d6,d7,d8,d9,d10,d11};
    const int ns[12] = {1048576,1048576,1048576,1048576,65536,65536,32768,32768,65536,65536,131072,131072};
    int t = blockIdx.y;
    int i = (blockIdx.x * 256 + threadIdx.x) * 4;
    if (i >= ns[t]) return;
    float4 v = *(const float4*)(srcs[t] + i);
    ushort4 o;
    o.x = f2bf(v.x); o.y = f2bf(v.y); o.z = f2bf(v.z); o.w = f2bf(v.w);
    *(ushort4*)(dsts[t] + i) = o;
}

// ---------------- token-shift mix: out_t = bf16(x + (x_prev - x) * mix_t) ----------------
__global__ __launch_bounds__(256) void mix_kernel(
    const float* __restrict__ x,
    const float* __restrict__ mr, const float* __restrict__ mw, const float* __restrict__ mk,
    const float* __restrict__ mv, const float* __restrict__ ma, const float* __restrict__ mg,
    u16* __restrict__ XR, u16* __restrict__ XW, u16* __restrict__ XK,
    u16* __restrict__ XV, u16* __restrict__ XA, u16* __restrict__ XG)
{
    int gi = blockIdx.x * 256 + threadIdx.x;     // 0 .. NTOK*Dx/4-1
    int n  = gi >> 8;                            // token
    int d4 = (gi & 255) << 2;                    // channel group of 4
    int l  = n & (Lx - 1);
    size_t o = (size_t)n * Dx + d4;
    float4 xc = *(const float4*)(x + o);
    float4 xp = make_float4(0.f, 0.f, 0.f, 0.f);
    if (l != 0) xp = *(const float4*)(x + o - Dx);
    float dx0 = xp.x - xc.x, dx1 = xp.y - xc.y, dx2 = xp.z - xc.z, dx3 = xp.w - xc.w;
    const float* mvs[6] = {mr, mw, mk, mv, ma, mg};
    u16* dsts[6] = {XR, XW, XK, XV, XA, XG};
#pragma unroll
    for (int j = 0; j < 6; ++j) {
        float4 m = *(const float4*)(mvs[j] + d4);
        ushort4 r;
        r.x = f2bf(fmaf(dx0, m.x, xc.x));
        r.y = f2bf(fmaf(dx1, m.y, xc.y));
        r.z = f2bf(fmaf(dx2, m.z, xc.z));
        r.w = f2bf(fmaf(dx3, m.w, xc.w));
        *(ushort4*)(dsts[j] + o) = r;
    }
}

// ---------------- bf16 MFMA GEMM, C[M,N] = act(A[M,K] . B[N,K]^T + bias_f32) ----------------
// ACT: 0 none, 1 sigmoid, 2 tanh, 3 exp(-0.606531*sigmoid)
template <int BN, int ACT, bool BIAS, bool F32OUT>
__global__ __launch_bounds__(256) void gemm_nt(
    const u16* __restrict__ A, const u16* __restrict__ Bm,
    const float* __restrict__ bias, void* __restrict__ Cv,
    int M, int N, int K)
{
    constexpr int BM = 128, BK = 32;
    constexpr int LDT = BK + 8;                    // +8 ushort pad: 80B rows, keeps 16B align
    constexpr int WGM = (BN == 128) ? 2 : 4;
    constexpr int WGN = (BN == 128) ? 2 : 1;
    constexpr int WTM = BM / WGM, WTN = BN / WGN;
    constexpr int ITM = WTM / 16, ITN = WTN / 16;
    __shared__ __align__(16) u16 Asm[BM * LDT];
    __shared__ __align__(16) u16 Bsm[BN * LDT];
    const int tid = threadIdx.x;
    const int wid = tid >> 6, lane = tid & 63;
    const int q = lane >> 4, r16 = lane & 15;
    const size_t m0 = (size_t)blockIdx.x * BM;
    const size_t n0 = (size_t)blockIdx.y * BN;
    const int wm = (wid % WGM) * WTM;
    const int wn = (wid / WGM) * WTN;
    f32x4 acc[ITM][ITN];
    const f32x4 zf = {0.f, 0.f, 0.f, 0.f};
#pragma unroll
    for (int i = 0; i < ITM; ++i)
#pragma unroll
        for (int j = 0; j < ITN; ++j) acc[i][j] = zf;

    for (int k0 = 0; k0 < K; k0 += BK) {
#pragma unroll
        for (int it = 0; it < (BM * BK) / 2048; ++it) {
            int pp = tid * 8 + it * 2048;
            int row = pp >> 5, col = pp & 31;
            *(uint4*)&Asm[row * LDT + col] = *(const uint4*)(A + (m0 + row) * K + k0 + col);
        }
        if constexpr (BN * BK >= 2048) {
#pragma unroll
            for (int it = 0; it < (BN * BK) / 2048; ++it) {
                int pp = tid * 8 + it * 2048;
                int row = pp >> 5, col = pp & 31;
                *(uint4*)&Bsm[row * LDT + col] = *(const uint4*)(Bm + (n0 + row) * K + k0 + col);
            }
        } else {
            int pp = tid * 8;
            if (pp < BN * BK) {
                int row = pp >> 5, col = pp & 31;
                *(uint4*)&Bsm[row * LDT + col] = *(const uint4*)(Bm + (n0 + row) * K + k0 + col);
            }
        }
        __syncthreads();
        bf16x8 af[ITM], bfr[ITN];
#pragma unroll
        for (int im = 0; im < ITM; ++im)
            af[im] = *(const bf16x8*)&Asm[(wm + im * 16 + r16) * LDT + q * 8];
#pragma unroll
        for (int in = 0; in < ITN; ++in)
            bfr[in] = *(const bf16x8*)&Bsm[(wn + in * 16 + r16) * LDT + q * 8];
#pragma unroll
        for (int im = 0; im < ITM; ++im)
#pragma unroll
            for (int in = 0; in < ITN; ++in)
                acc[im][in] = __builtin_amdgcn_mfma_f32_16x16x32_bf16(af[im], bfr[in], acc[im][in], 0, 0, 0);
        __syncthreads();
    }
    // epilogue: C/D layout col = lane&15 (n), row = quad*4+reg (m)  [m89-verified]
#pragma unroll
    for (int im = 0; im < ITM; ++im) {
#pragma unroll
        for (int in = 0; in < ITN; ++in) {
#pragma unroll
            for (int e = 0; e < 4; ++e) {
                size_t row = m0 + wm + im * 16 + q * 4 + e;
                size_t col = n0 + wn + in * 16 + r16;
                float val = acc[im][in][e];
                if constexpr (BIAS) val += bias[col];
                if constexpr (ACT == 1) val = 1.f / (1.f + __expf(-val));
                else if constexpr (ACT == 2) val = tanhf(val);
                else if constexpr (ACT == 3) val = __expf(-0.606531f / (1.f + __expf(-val)));
                if constexpr (F32OUT) ((float*)Cv)[row * (size_t)N + col] = val;
                else ((u16*)Cv)[row * (size_t)N + col] = f2bf(val);
            }
        }
    }
}

// ---------------- prep: kk-normalize, a/b vectors, k/v updates ----------------
__global__ __launch_bounds__(256) void prep_kernel(
    u16* __restrict__ Kb, u16* __restrict__ Vb,
    const u16* __restrict__ ICLR, const u16* __restrict__ VVb, const float* __restrict__ vfirst,
    const float* __restrict__ k_k, const float* __restrict__ k_a,
    u16* __restrict__ Av, u16* __restrict__ Bv)
{
    int g = blockIdx.x * 4 + (threadIdx.x >> 6);   // (token,head) pair
    int lane = threadIdx.x & 63;
    int h = g & (Hx - 1);
    size_t idx = (size_t)g * 64 + lane;            // == n*1024 + h*64 + lane
    int hd = h * 64 + lane;
    float k = bf2f(Kb[idx]);
    float iclr = bf2f(ICLR[idx]);
    float kkn = k * k_k[hd];
    float s = kkn * kkn;
#pragma unroll
    for (int off = 32; off > 0; off >>= 1) s += __shfl_xor(s, off, 64);
    float nrm = fmaxf(sqrtf(s), 1e-7f);
    float kk = kkn / nrm;
    Av[idx] = f2bf(-kk);
    Bv[idx] = f2bf(kk * iclr);
    Kb[idx] = f2bf(k * (1.f + (iclr - 1.f) * k_a[hd]));
    float v = bf2f(Vb[idx]), vv = bf2f(VVb[idx]), vf = vfirst[idx];
    Vb[idx] = f2bf(fmaf(vf - v, vv, v));
}

// ---------------- WKV7 scan: 4 waves per (b,h); wave w owns cols [16w,16w+16), lane owns row ----------------
__global__ __launch_bounds__(256, 1) void scan_kernel(
    const u16* __restrict__ Rb, const float* __restrict__ Wd,
    const u16* __restrict__ Kb, const u16* __restrict__ Vb,
    const u16* __restrict__ Av, const u16* __restrict__ Bv,
    float* __restrict__ Y)
{
    const int bh = blockIdx.x;                    // b*16+h
    const int tid = threadIdx.x;
    const int lane = tid & 63;                    // row i
    const int w = tid >> 6;                       // column group
    const size_t base = (size_t)(bh >> 4) * ((size_t)Lx * Dx) + (size_t)(bh & 15) * 64;
    __shared__ __align__(16) float shv[2][5 * 64];   // [buf][r|w|k|a|b]
    __shared__ __align__(16) float part[4 * 64];     // sa partials [w][i]
    __shared__ __align__(16) float ypart[4 * 64];    // y partials [w][i]

    float S[16];
#pragma unroll
    for (int c = 0; c < 16; ++c) S[c] = 0.f;

    // prefetch t=0: wave0 -> r + decay, wave1 -> k, wave2 -> a, wave3 -> b; all -> v(row)
    float p0, p1 = 0.f, pv;
    {
        size_t o0 = base + lane;
        if (w == 0)      { p0 = bf2f(Rb[o0]); p1 = Wd[o0]; }
        else if (w == 1) { p0 = bf2f(Kb[o0]); }
        else if (w == 2) { p0 = bf2f(Av[o0]); }
        else             { p0 = bf2f(Bv[o0]); }
        pv = bf2f(Vb[o0]);
    }

    for (int t = 0; t < Lx; ++t) {
        float* sv = shv[t & 1];
        if (w == 0)      { sv[lane] = p0; sv[64 + lane] = p1; }
        else if (w == 1) { sv[128 + lane] = p0; }
        else if (w == 2) { sv[192 + lane] = p0; }
        else             { sv[256 + lane] = p0; }
        const float v = pv;
        __syncthreads();                           // barrier A: shv(t) visible
        // finish y(t-1): ypart written before barrier A, next write after barrier B
        if (t > 0 && w == 0) {
            float ys = (ypart[lane] + ypart[64 + lane]) + (ypart[128 + lane] + ypart[192 + lane]);
            Y[base + (size_t)(t - 1) * Dx + lane] = ys;
        }
        if (t + 1 < Lx) {                          // prefetch t+1, overlaps compute
            size_t o1 = base + (size_t)(t + 1) * Dx + lane;
            if (w == 0)      { p0 = bf2f(Rb[o1]); p1 = Wd[o1]; }
            else if (w == 1) { p0 = bf2f(Kb[o1]); }
            else if (w == 2) { p0 = bf2f(Av[o1]); }
            else             { p0 = bf2f(Bv[o1]); }
            pv = bf2f(Vb[o1]);
        }
        // sa partial over this wave's 16 columns
        const float4* a4p = (const float4*)(sv + 192 + 16 * w);
        float pp0 = 0.f, pp1 = 0.f, pp2 = 0.f, pp3 = 0.f;
#pragma unroll
        for (int q2 = 0; q2 < 4; ++q2) {
            float4 a4 = a4p[q2];
            pp0 = fmaf(S[4 * q2 + 0], a4.x, pp0);
            pp1 = fmaf(S[4 * q2 + 1], a4.y, pp1);
            pp2 = fmaf(S[4 * q2 + 2], a4.z, pp2);
            pp3 = fmaf(S[4 * q2 + 3], a4.w, pp3);
        }
        part[w * 64 + lane] = (pp0 + pp1) + (pp2 + pp3);
        __syncthreads();                           // barrier B: partials visible
        const float sa = (part[lane] + part[64 + lane]) + (part[128 + lane] + part[192 + lane]);
        // update S + y partial
        const float4* w4p = (const float4*)(sv + 64 + 16 * w);
        const float4* k4p = (const float4*)(sv + 128 + 16 * w);
        const float4* b4p = (const float4*)(sv + 256 + 16 * w);
        const float4* r4p = (const float4*)(sv + 16 * w);
        float y0 = 0.f, y1 = 0.f, y2 = 0.f, y3 = 0.f;
#pragma unroll
        for (int q2 = 0; q2 < 4; ++q2) {
            float4 w4 = w4p[q2], k4 = k4p[q2], b4 = b4p[q2], r4 = r4p[q2];
            float s;
            s = fmaf(S[4 * q2 + 0], w4.x, fmaf(v, k4.x, sa * b4.x)); S[4 * q2 + 0] = s; y0 = fmaf(s, r4.x, y0);
            s = fmaf(S[4 * q2 + 1], w4.y, fmaf(v, k4.y, sa * b4.y)); S[4 * q2 + 1] = s; y1 = fmaf(s, r4.y, y1);
            s = fmaf(S[4 * q2 + 2], w4.z, fmaf(v, k4.z, sa * b4.z)); S[4 * q2 + 2] = s; y2 = fmaf(s, r4.z, y2);
            s = fmaf(S[4 * q2 + 3], w4.w, fmaf(v, k4.w, sa * b4.w)); S[4 * q2 + 3] = s; y3 = fmaf(s, r4.w, y3);
        }
        ypart[w * 64 + lane] = (y0 + y1) + (y2 + y3);
    }
    __syncthreads();
    if (w == 0) {
        float ys = (ypart[lane] + ypart[64 + lane]) + (ypart[128 + lane] + ypart[192 + lane]);
        Y[base + (size_t)(Lx - 1) * Dx + lane] = ys;
    }
}

// ---------------- group-norm + rkr residual + gate (OG written in-place over GATE) ----------------
__global__ __launch_bounds__(256) void gnorm_kernel(
    const float* __restrict__ Y, const u16* __restrict__ Rb, const u16* __restrict__ Kb,
    const u16* __restrict__ Vb, const float* __restrict__ r_k,
    const float* __restrict__ gnw, const float* __restrict__ gnb,
    u16* __restrict__ GATE_OG)
{
    int g = blockIdx.x * 4 + (threadIdx.x >> 6);
    int lane = threadIdx.x & 63;
    int h = g & (Hx - 1);
    size_t idx = (size_t)g * 64 + lane;
    int hd = h * 64 + lane;
    float y = Y[idx];
    float r = bf2f(Rb[idx]), k = bf2f(Kb[idx]), v = bf2f(Vb[idx]);
    float rkr = r * k * r_k[hd];
    float s1 = y, s2 = y * y, s3 = rkr;
#pragma unroll
    for (int off = 32; off > 0; off >>= 1) {
        s1 += __shfl_xor(s1, off, 64);
        s2 += __shfl_xor(s2, off, 64);
        s3 += __shfl_xor(s3, off, 64);
    }
    float mean = s1 * (1.f / 64.f);
    float var  = s2 * (1.f / 64.f) - mean * mean;
    float inv = 1.f / sqrtf(var + EPS_GN);
    float o = gnw[hd] * ((y - mean) * inv) + gnb[hd];
    o += s3 * v;
    GATE_OG[idx] = f2bf(o * bf2f(GATE_OG[idx]));
}

// ---------------- launch ----------------
extern "C" void kernel_launch(void* const* d_in, const int* in_sizes, int n_in,
                              void* d_out, int out_size, void* d_ws, size_t ws_size,
                              hipStream_t stream)
{
    const float* x      = (const float*)d_in[0];
    const float* vfirst = (const float*)d_in[1];
    const float* x_r = (const float*)d_in[2];
    const float* x_w = (const float*)d_in[3];
    const float* x_k = (const float*)d_in[4];
    const float* x_v = (const float*)d_in[5];
    const float* x_a = (const float*)d_in[6];
    const float* x_g = (const float*)d_in[7];
    const float* k_k = (const float*)d_in[8];
    const float* k_a = (const float*)d_in[9];
    const float* r_k = (const float*)d_in[10];
    const float* Wr  = (const float*)d_in[11];
    const float* Wk  = (const float*)d_in[12];
    const float* Wv  = (const float*)d_in[13];
    const float* Wo  = (const float*)d_in[14];
    const float* gnw = (const float*)d_in[15];
    const float* gnb = (const float*)d_in[16];
    const float* wA  = (const float*)d_in[17];
    const float* wB  = (const float*)d_in[18];
    const float* wb  = (const float*)d_in[19];
    const float* vA  = (const float*)d_in[20];
    const float* vB  = (const float*)d_in[21];
    const float* vb  = (const float*)d_in[22];
    const float* aA  = (const float*)d_in[23];
    const float* aB  = (const float*)d_in[24];
    const float* ab  = (const float*)d_in[25];
    const float* gA  = (const float*)d_in[26];
    const float* gB  = (const float*)d_in[27];

    char* ws = (char*)d_ws;
    const size_t SLOT = (size_t)NTOK * Dx * 2;   // 16 MiB; 14 slots (~224 MiB)
    u16* XR = (u16*)(ws + 0 * SLOT);
    u16* XW = (u16*)(ws + 1 * SLOT);
    u16* XK = (u16*)(ws + 2 * SLOT);
    u16* XV = (u16*)(ws + 3 * SLOT);
    u16* XA = (u16*)(ws + 4 * SLOT);
    u16* XG = (u16*)(ws + 5 * SLOT);
    u16* Rbuf = (u16*)(ws + 6 * SLOT);
    u16* Kbuf = (u16*)(ws + 7 * SLOT);
    u16* Vbuf = (u16*)(ws + 8 * SLOT);
    u16* HW = (u16*)(ws + 9 * SLOT);             // slot 9 holds all 4 lora hiddens
    u16* HA = HW + (size_t)NTOK * 64;
    u16* HV = HA + (size_t)NTOK * 64;
    u16* HG = HV + (size_t)NTOK * 32;
    u16* Bvec = (u16*)(ws + 10 * SLOT);
    float* Yb = (float*)(ws + 11 * SLOT);        // slots 11-12 (fp32)
    // slot 13: converted bf16 weights (~9.2 MiB used)
    u16* WrB = (u16*)(ws + 13 * SLOT);
    u16* WkB = WrB + 1048576;
    u16* WvB = WkB + 1048576;
    u16* WoB = WvB + 1048576;
    u16* wAB = WoB + 1048576;
    u16* wBB = wAB + 65536;
    u16* vAB = wBB + 65536;
    u16* vBB = vAB + 32768;
    u16* aAB = vBB + 32768;
    u16* aBB = aAB + 65536;
    u16* gAB = aBB + 65536;
    u16* gBB = gAB + 131072;
    // reuse of consumed mix slots:
    float* Wdec = (float*)(ws + 0 * SLOT);       // slots 0-1 (fp32 decay)
    u16* ICLR = (u16*)(ws + 2 * SLOT);
    u16* VVb  = (u16*)(ws + 3 * SLOT);
    u16* GATE = (u16*)(ws + 4 * SLOT);           // gnorm writes OG in-place here
    u16* Avec = (u16*)(ws + 5 * SLOT);

    dim3 blk(256);
    conv_kernel<<<dim3(1024, 12), blk, 0, stream>>>(Wr, Wk, Wv, Wo, wA, wB, vA, vB, aA, aB, gA, gB,
                                                    WrB, WkB, WvB, WoB, wAB, wBB, vAB, vBB, aAB, aBB, gAB, gBB);
    mix_kernel<<<(NTOK * Dx / 4) / 256, blk, 0, stream>>>(x, x_r, x_w, x_k, x_v, x_a, x_g,
                                                          XR, XW, XK, XV, XA, XG);
    // big projections
    gemm_nt<128, 0, false, false><<<dim3(64, 8), blk, 0, stream>>>(XR, WrB, nullptr, Rbuf, NTOK, 1024, 1024);
    gemm_nt<128, 0, false, false><<<dim3(64, 8), blk, 0, stream>>>(XK, WkB, nullptr, Kbuf, NTOK, 1024, 1024);
    gemm_nt<128, 0, false, false><<<dim3(64, 8), blk, 0, stream>>>(XV, WvB, nullptr, Vbuf, NTOK, 1024, 1024);
    // lora stage 1 (down-proj)
    gemm_nt<64, 2, false, false><<<dim3(64, 1), blk, 0, stream>>>(XW, wAB, nullptr, HW, NTOK, 64, 1024);
    gemm_nt<64, 0, false, false><<<dim3(64, 1), blk, 0, stream>>>(XA, aAB, nullptr, HA, NTOK, 64, 1024);
    gemm_nt<32, 0, false, false><<<dim3(64, 1), blk, 0, stream>>>(XV, vAB, nullptr, HV, NTOK, 32, 1024);
    gemm_nt<128, 1, false, false><<<dim3(64, 1), blk, 0, stream>>>(XG, gAB, nullptr, HG, NTOK, 128, 1024);
    // lora stage 2 (up-proj, fused epilogues); mix slots now free for reuse
    gemm_nt<128, 3, true,  true ><<<dim3(64, 8), blk, 0, stream>>>(HW, wBB, wb, Wdec, NTOK, 1024, 64);
    gemm_nt<128, 1, true,  false><<<dim3(64, 8), blk, 0, stream>>>(HA, aBB, ab, ICLR, NTOK, 1024, 64);
    gemm_nt<128, 1, true,  false><<<dim3(64, 8), blk, 0, stream>>>(HV, vBB, vb, VVb, NTOK, 1024, 32);
    gemm_nt<128, 0, false, false><<<dim3(64, 8), blk, 0, stream>>>(HG, gBB, nullptr, GATE, NTOK, 1024, 128);

    prep_kernel<<<(NTOK * Hx) / 4, blk, 0, stream>>>(Kbuf, Vbuf, ICLR, VVb, vfirst, k_k, k_a, Avec, Bvec);
    scan_kernel<<<Bx * Hx, 256, 0, stream>>>(Rbuf, Wdec, Kbuf, Vbuf, Avec, Bvec, Yb);
    gnorm_kernel<<<(NTOK * Hx) / 4, blk, 0, stream>>>(Yb, Rbuf, Kbuf, Vbuf, r_k, gnw, gnb, GATE);
    gemm_nt<128, 0, false, true><<<dim3(64, 8), blk, 0, stream>>>(GATE, WoB, nullptr, d_out, NTOK, 1024, 1024);
}

// Round 4
// 1786.218 us; speedup vs baseline: 2.5211x; 1.1181x over previous
//
#include <hip/hip_runtime.h>
#include <cmath>

// RWKV7 time-mixing, B=4 L=2048 D=1024 H=16 Dh=64. Inputs/outputs fp32; internal bf16 MFMA.
// Pipeline: convert-weights -> mix -> [r,k,v,lora1x4] GEMMs -> [lora2x4] GEMMs -> prep -> scan -> gnorm -> out GEMM.

#define DEV __device__ __forceinline__

typedef unsigned short u16;
typedef unsigned int u32;
typedef __bf16 bf16x8 __attribute__((ext_vector_type(8)));
typedef float f32x4 __attribute__((ext_vector_type(4)));

constexpr int Bx = 4, Lx = 2048, Dx = 1024, Hx = 16, Dh = 64;
constexpr int NTOK = Bx * Lx;       // 8192
constexpr float EPS_GN = 0.00064f;

DEV float bf2f(u16 u) { union { u32 i; float f; } c; c.i = ((u32)u) << 16; return c.f; }
DEV u16 f2bf(float f) {
    union { float f; u32 i; } c; c.f = f;
    u32 r = c.i + 0x7FFFu + ((c.i >> 16) & 1u);
    return (u16)(r >> 16);
}
DEV void unpack2(u32 u, float& a, float& b) {
    union { u32 i; float f; } c0, c1;
    c0.i = u << 16; c1.i = u & 0xFFFF0000u;
    a = c0.f; b = c1.f;
}
DEV void unpack8(const uint4& v, float* f) {
    unpack2(v.x, f[0], f[1]); unpack2(v.y, f[2], f[3]);
    unpack2(v.z, f[4], f[5]); unpack2(v.w, f[6], f[7]);
}

// ---------------- weight f32 -> bf16 conversion (12 tensors, one dispatch) ----------------
__global__ __launch_bounds__(256) void conv_kernel(
    const float* s0, const float* s1, const float* s2, const float* s3,
    const float* s4, const float* s5, const float* s6, const float* s7,
    const float* s8, const float* s9, const float* s10, const float* s11,
    u16* d0, u16* d1, u16* d2, u16* d3, u16* d4, u16* d5,
    u16* d6, u16* d7, u16* d8, u16* d9, u16* d10, u16* d11)
{
    const float* srcs[12] = {s0,s1,s2,s3,s4,s5,s6,s7,s8,s9,s10,s11};
    u16* dsts[12] = {d0,d1,d2,d3,d4,d5,d6,d7,d8,d9,d10,d11};
    const int ns[12] = {1048576,1048576,1048576,1048576,65536,65536,32768,32768,65536,65536,131072,131072};
    int t = blockIdx.y;
    int i = (blockIdx.x * 256 + threadIdx.x) * 4;
    if (i >= ns[t]) return;
    float4 v = *(const float4*)(srcs[t] + i);
    ushort4 o;
    o.x = f2bf(v.x); o.y = f2bf(v.y); o.z = f2bf(v.z); o.w = f2bf(v.w);
    *(ushort4*)(dsts[t] + i) = o;
}

// ---------------- token-shift mix: out_t = bf16(x + (x_prev - x) * mix_t) ----------------
__global__ __launch_bounds__(256) void mix_kernel(
    const float* __restrict__ x,
    const float* __restrict__ mr, const float* __restrict__ mw, const float* __restrict__ mk,
    const float* __restrict__ mv, const float* __restrict__ ma, const float* __restrict__ mg,
    u16* __restrict__ XR, u16* __restrict__ XW, u16* __restrict__ XK,
    u16* __restrict__ XV, u16* __restrict__ XA, u16* __restrict__ XG)
{
    int gi = blockIdx.x * 256 + threadIdx.x;     // 0 .. NTOK*Dx/4-1
    int n  = gi >> 8;                            // token
    int d4 = (gi & 255) << 2;                    // channel group of 4
    int l  = n & (Lx - 1);
    size_t o = (size_t)n * Dx + d4;
    float4 xc = *(const float4*)(x + o);
    float4 xp = make_float4(0.f, 0.f, 0.f, 0.f);
    if (l != 0) xp = *(const float4*)(x + o - Dx);
    float dx0 = xp.x - xc.x, dx1 = xp.y - xc.y, dx2 = xp.z - xc.z, dx3 = xp.w - xc.w;
    const float* mvs[6] = {mr, mw, mk, mv, ma, mg};
    u16* dsts[6] = {XR, XW, XK, XV, XA, XG};
#pragma unroll
    for (int j = 0; j < 6; ++j) {
        float4 m = *(const float4*)(mvs[j] + d4);
        ushort4 r;
        r.x = f2bf(fmaf(dx0, m.x, xc.x));
        r.y = f2bf(fmaf(dx1, m.y, xc.y));
        r.z = f2bf(fmaf(dx2, m.z, xc.z));
        r.w = f2bf(fmaf(dx3, m.w, xc.w));
        *(ushort4*)(dsts[j] + o) = r;
    }
}

// ---------------- bf16 MFMA GEMM, C[M,N] = act(A[M,K] . B[N,K]^T + bias_f32) ----------------
// ACT: 0 none, 1 sigmoid, 2 tanh, 3 exp(-0.606531*sigmoid)
template <int BN, int ACT, bool BIAS, bool F32OUT>
__global__ __launch_bounds__(256) void gemm_nt(
    const u16* __restrict__ A, const u16* __restrict__ Bm,
    const float* __restrict__ bias, void* __restrict__ Cv,
    int M, int N, int K)
{
    constexpr int BM = 128, BK = 32;
    constexpr int LDT = BK + 8;                    // +8 ushort pad: 80B rows, keeps 16B align
    constexpr int WGM = (BN == 128) ? 2 : 4;
    constexpr int WGN = (BN == 128) ? 2 : 1;
    constexpr int WTM = BM / WGM, WTN = BN / WGN;
    constexpr int ITM = WTM / 16, ITN = WTN / 16;
    __shared__ __align__(16) u16 Asm[BM * LDT];
    __shared__ __align__(16) u16 Bsm[BN * LDT];
    const int tid = threadIdx.x;
    const int wid = tid >> 6, lane = tid & 63;
    const int q = lane >> 4, r16 = lane & 15;
    const size_t m0 = (size_t)blockIdx.x * BM;
    const size_t n0 = (size_t)blockIdx.y * BN;
    const int wm = (wid % WGM) * WTM;
    const int wn = (wid / WGM) * WTN;
    f32x4 acc[ITM][ITN];
    const f32x4 zf = {0.f, 0.f, 0.f, 0.f};
#pragma unroll
    for (int i = 0; i < ITM; ++i)
#pragma unroll
        for (int j = 0; j < ITN; ++j) acc[i][j] = zf;

    for (int k0 = 0; k0 < K; k0 += BK) {
#pragma unroll
        for (int it = 0; it < (BM * BK) / 2048; ++it) {
            int pp = tid * 8 + it * 2048;
            int row = pp >> 5, col = pp & 31;
            *(uint4*)&Asm[row * LDT + col] = *(const uint4*)(A + (m0 + row) * K + k0 + col);
        }
        if constexpr (BN * BK >= 2048) {
#pragma unroll
            for (int it = 0; it < (BN * BK) / 2048; ++it) {
                int pp = tid * 8 + it * 2048;
                int row = pp >> 5, col = pp & 31;
                *(uint4*)&Bsm[row * LDT + col] = *(const uint4*)(Bm + (n0 + row) * K + k0 + col);
            }
        } else {
            int pp = tid * 8;
            if (pp < BN * BK) {
                int row = pp >> 5, col = pp & 31;
                *(uint4*)&Bsm[row * LDT + col] = *(const uint4*)(Bm + (n0 + row) * K + k0 + col);
            }
        }
        __syncthreads();
        bf16x8 af[ITM], bfr[ITN];
#pragma unroll
        for (int im = 0; im < ITM; ++im)
            af[im] = *(const bf16x8*)&Asm[(wm + im * 16 + r16) * LDT + q * 8];
#pragma unroll
        for (int in = 0; in < ITN; ++in)
            bfr[in] = *(const bf16x8*)&Bsm[(wn + in * 16 + r16) * LDT + q * 8];
#pragma unroll
        for (int im = 0; im < ITM; ++im)
#pragma unroll
            for (int in = 0; in < ITN; ++in)
                acc[im][in] = __builtin_amdgcn_mfma_f32_16x16x32_bf16(af[im], bfr[in], acc[im][in], 0, 0, 0);
        __syncthreads();
    }
    // epilogue: C/D layout col = lane&15 (n), row = quad*4+reg (m)  [m89-verified]
#pragma unroll
    for (int im = 0; im < ITM; ++im) {
#pragma unroll
        for (int in = 0; in < ITN; ++in) {
#pragma unroll
            for (int e = 0; e < 4; ++e) {
                size_t row = m0 + wm + im * 16 + q * 4 + e;
                size_t col = n0 + wn + in * 16 + r16;
                float val = acc[im][in][e];
                if constexpr (BIAS) val += bias[col];
                if constexpr (ACT == 1) val = 1.f / (1.f + __expf(-val));
                else if constexpr (ACT == 2) val = tanhf(val);
                else if constexpr (ACT == 3) val = __expf(-0.606531f / (1.f + __expf(-val)));
                if constexpr (F32OUT) ((float*)Cv)[row * (size_t)N + col] = val;
                else ((u16*)Cv)[row * (size_t)N + col] = f2bf(val);
            }
        }
    }
}

// ---------------- prep: kk-normalize, a/b vectors, k/v updates ----------------
__global__ __launch_bounds__(256) void prep_kernel(
    u16* __restrict__ Kb, u16* __restrict__ Vb,
    const u16* __restrict__ ICLR, const u16* __restrict__ VVb, const float* __restrict__ vfirst,
    const float* __restrict__ k_k, const float* __restrict__ k_a,
    u16* __restrict__ Av, u16* __restrict__ Bv)
{
    int g = blockIdx.x * 4 + (threadIdx.x >> 6);   // (token,head) pair
    int lane = threadIdx.x & 63;
    int h = g & (Hx - 1);
    size_t idx = (size_t)g * 64 + lane;            // == n*1024 + h*64 + lane
    int hd = h * 64 + lane;
    float k = bf2f(Kb[idx]);
    float iclr = bf2f(ICLR[idx]);
    float kkn = k * k_k[hd];
    float s = kkn * kkn;
#pragma unroll
    for (int off = 32; off > 0; off >>= 1) s += __shfl_xor(s, off, 64);
    float nrm = fmaxf(sqrtf(s), 1e-7f);
    float kk = kkn / nrm;
    Av[idx] = f2bf(-kk);
    Bv[idx] = f2bf(kk * iclr);
    Kb[idx] = f2bf(k * (1.f + (iclr - 1.f) * k_a[hd]));
    float v = bf2f(Vb[idx]), vv = bf2f(VVb[idx]), vf = vfirst[idx];
    Vb[idx] = f2bf(fmaf(vf - v, vv, v));
}

// ---------------- WKV7 scan v3: wave-local, barrier-free ----------------
// 8 waves per (b,h); wave owns 8 rows x 64 cols. Lane: row = 8*widx + (lane&7),
// cols [8*(lane>>3), +8) -> S[8]/thread. sa & y reductions via shfl_xor(8,16,32)
// across the 8 col-groups of a row (all in-wave). No LDS, no __syncthreads.
struct SBuf { uint4 r, k, a, b; float4 w0, w1; float v; };

DEV void scan_load(SBuf& s, const u16* Rb, const float* Wd, const u16* Kb,
                   const u16* Vb, const u16* Av, const u16* Bv,
                   size_t vecoff, size_t voff)
{
    s.r = *(const uint4*)(Rb + vecoff);
    s.k = *(const uint4*)(Kb + vecoff);
    s.a = *(const uint4*)(Av + vecoff);
    s.b = *(const uint4*)(Bv + vecoff);
    s.w0 = *(const float4*)(Wd + vecoff);
    s.w1 = *(const float4*)(Wd + vecoff + 4);
    s.v = bf2f(Vb[voff]);
}

DEV void scan_step(float* S, const SBuf& sb, float* Yp, int cg)
{
    float r[8], k[8], a[8], b[8];
    unpack8(sb.r, r); unpack8(sb.k, k); unpack8(sb.a, a); unpack8(sb.b, b);
    const float w[8] = {sb.w0.x, sb.w0.y, sb.w0.z, sb.w0.w,
                        sb.w1.x, sb.w1.y, sb.w1.z, sb.w1.w};
    float sa0 = 0.f, sa1 = 0.f;
#pragma unroll
    for (int c = 0; c < 8; c += 2) {
        sa0 = fmaf(S[c], a[c], sa0);
        sa1 = fmaf(S[c + 1], a[c + 1], sa1);
    }
    float sa = sa0 + sa1;
    sa += __shfl_xor(sa, 8, 64);
    sa += __shfl_xor(sa, 16, 64);
    sa += __shfl_xor(sa, 32, 64);
    float y0 = 0.f, y1 = 0.f;
#pragma unroll
    for (int c = 0; c < 8; c += 2) {
        float s0 = fmaf(S[c], w[c], fmaf(sb.v, k[c], sa * b[c]));
        float s1 = fmaf(S[c + 1], w[c + 1], fmaf(sb.v, k[c + 1], sa * b[c + 1]));
        S[c] = s0; S[c + 1] = s1;
        y0 = fmaf(s0, r[c], y0);
        y1 = fmaf(s1, r[c + 1], y1);
    }
    float y = y0 + y1;
    y += __shfl_xor(y, 8, 64);
    y += __shfl_xor(y, 16, 64);
    y += __shfl_xor(y, 32, 64);
    if (cg == 0) *Yp = y;
}

__global__ __launch_bounds__(256, 1) void scan_kernel(
    const u16* __restrict__ Rb, const float* __restrict__ Wd,
    const u16* __restrict__ Kb, const u16* __restrict__ Vb,
    const u16* __restrict__ Av, const u16* __restrict__ Bv,
    float* __restrict__ Y)
{
    const int blk = blockIdx.x;                   // 0..127
    const int bh = blk >> 1;                      // b*16+h
    const int tid = threadIdx.x;
    const int lane = tid & 63;
    const int widx = ((blk & 1) << 2) | (tid >> 6);  // 0..7
    const int rowidx = lane & 7, cg = lane >> 3;
    const int row = widx * 8 + rowidx;
    const int col0 = cg * 8;
    const size_t base = (size_t)(bh >> 4) * ((size_t)Lx * Dx) + (size_t)(bh & 15) * 64;
    const size_t vec0 = base + col0;
    const size_t v0 = base + row;

    float S[8];
#pragma unroll
    for (int c = 0; c < 8; ++c) S[c] = 0.f;

    SBuf bufA, bufB;
    scan_load(bufA, Rb, Wd, Kb, Vb, Av, Bv, vec0, v0);             // t=0
    scan_load(bufB, Rb, Wd, Kb, Vb, Av, Bv, vec0 + Dx, v0 + Dx);   // t=1

    for (int t = 0; t < Lx; t += 2) {
        scan_step(S, bufA, Y + base + (size_t)t * Dx + row, cg);
        if (t + 2 < Lx)
            scan_load(bufA, Rb, Wd, Kb, Vb, Av, Bv,
                      vec0 + (size_t)(t + 2) * Dx, v0 + (size_t)(t + 2) * Dx);
        scan_step(S, bufB, Y + base + (size_t)(t + 1) * Dx + row, cg);
        if (t + 3 < Lx)
            scan_load(bufB, Rb, Wd, Kb, Vb, Av, Bv,
                      vec0 + (size_t)(t + 3) * Dx, v0 + (size_t)(t + 3) * Dx);
    }
}

// ---------------- group-norm + rkr residual + gate (OG written in-place over GATE) ----------------
__global__ __launch_bounds__(256) void gnorm_kernel(
    const float* __restrict__ Y, const u16* __restrict__ Rb, const u16* __restrict__ Kb,
    const u16* __restrict__ Vb, const float* __restrict__ r_k,
    const float* __restrict__ gnw, const float* __restrict__ gnb,
    u16* __restrict__ GATE_OG)
{
    int g = blockIdx.x * 4 + (threadIdx.x >> 6);
    int lane = threadIdx.x & 63;
    int h = g & (Hx - 1);
    size_t idx = (size_t)g * 64 + lane;
    int hd = h * 64 + lane;
    float y = Y[idx];
    float r = bf2f(Rb[idx]), k = bf2f(Kb[idx]), v = bf2f(Vb[idx]);
    float rkr = r * k * r_k[hd];
    float s1 = y, s2 = y * y, s3 = rkr;
#pragma unroll
    for (int off = 32; off > 0; off >>= 1) {
        s1 += __shfl_xor(s1, off, 64);
        s2 += __shfl_xor(s2, off, 64);
        s3 += __shfl_xor(s3, off, 64);
    }
    float mean = s1 * (1.f / 64.f);
    float var  = s2 * (1.f / 64.f) - mean * mean;
    float inv = 1.f / sqrtf(var + EPS_GN);
    float o = gnw[hd] * ((y - mean) * inv) + gnb[hd];
    o += s3 * v;
    GATE_OG[idx] = f2bf(o * bf2f(GATE_OG[idx]));
}

// ---------------- launch ----------------
extern "C" void kernel_launch(void* const* d_in, const int* in_sizes, int n_in,
                              void* d_out, int out_size, void* d_ws, size_t ws_size,
                              hipStream_t stream)
{
    const float* x      = (const float*)d_in[0];
    const float* vfirst = (const float*)d_in[1];
    const float* x_r = (const float*)d_in[2];
    const float* x_w = (const float*)d_in[3];
    const float* x_k = (const float*)d_in[4];
    const float* x_v = (const float*)d_in[5];
    const float* x_a = (const float*)d_in[6];
    const float* x_g = (const float*)d_in[7];
    const float* k_k = (const float*)d_in[8];
    const float* k_a = (const float*)d_in[9];
    const float* r_k = (const float*)d_in[10];
    const float* Wr  = (const float*)d_in[11];
    const float* Wk  = (const float*)d_in[12];
    const float* Wv  = (const float*)d_in[13];
    const float* Wo  = (const float*)d_in[14];
    const float* gnw = (const float*)d_in[15];
    const float* gnb = (const float*)d_in[16];
    const float* wA  = (const float*)d_in[17];
    const float* wB  = (const float*)d_in[18];
    const float* wb  = (const float*)d_in[19];
    const float* vA  = (const float*)d_in[20];
    const float* vB  = (const float*)d_in[21];
    const float* vb  = (const float*)d_in[22];
    const float* aA  = (const float*)d_in[23];
    const float* aB  = (const float*)d_in[24];
    const float* ab  = (const float*)d_in[25];
    const float* gA  = (const float*)d_in[26];
    const float* gB  = (const float*)d_in[27];

    char* ws = (char*)d_ws;
    const size_t SLOT = (size_t)NTOK * Dx * 2;   // 16 MiB; 14 slots (~224 MiB)
    u16* XR = (u16*)(ws + 0 * SLOT);
    u16* XW = (u16*)(ws + 1 * SLOT);
    u16* XK = (u16*)(ws + 2 * SLOT);
    u16* XV = (u16*)(ws + 3 * SLOT);
    u16* XA = (u16*)(ws + 4 * SLOT);
    u16* XG = (u16*)(ws + 5 * SLOT);
    u16* Rbuf = (u16*)(ws + 6 * SLOT);
    u16* Kbuf = (u16*)(ws + 7 * SLOT);
    u16* Vbuf = (u16*)(ws + 8 * SLOT);
    u16* HW = (u16*)(ws + 9 * SLOT);             // slot 9 holds all 4 lora hiddens
    u16* HA = HW + (size_t)NTOK * 64;
    u16* HV = HA + (size_t)NTOK * 64;
    u16* HG = HV + (size_t)NTOK * 32;
    u16* Bvec = (u16*)(ws + 10 * SLOT);
    float* Yb = (float*)(ws + 11 * SLOT);        // slots 11-12 (fp32)
    // slot 13: converted bf16 weights (~9.2 MiB used)
    u16* WrB = (u16*)(ws + 13 * SLOT);
    u16* WkB = WrB + 1048576;
    u16* WvB = WkB + 1048576;
    u16* WoB = WvB + 1048576;
    u16* wAB = WoB + 1048576;
    u16* wBB = wAB + 65536;
    u16* vAB = wBB + 65536;
    u16* vBB = vAB + 32768;
    u16* aAB = vBB + 32768;
    u16* aBB = aAB + 65536;
    u16* gAB = aBB + 65536;
    u16* gBB = gAB + 131072;
    // reuse of consumed mix slots:
    float* Wdec = (float*)(ws + 0 * SLOT);       // slots 0-1 (fp32 decay)
    u16* ICLR = (u16*)(ws + 2 * SLOT);
    u16* VVb  = (u16*)(ws + 3 * SLOT);
    u16* GATE = (u16*)(ws + 4 * SLOT);           // gnorm writes OG in-place here
    u16* Avec = (u16*)(ws + 5 * SLOT);

    dim3 blk(256);
    conv_kernel<<<dim3(1024, 12), blk, 0, stream>>>(Wr, Wk, Wv, Wo, wA, wB, vA, vB, aA, aB, gA, gB,
                                                    WrB, WkB, WvB, WoB, wAB, wBB, vAB, vBB, aAB, aBB, gAB, gBB);
    mix_kernel<<<(NTOK * Dx / 4) / 256, blk, 0, stream>>>(x, x_r, x_w, x_k, x_v, x_a, x_g,
                                                          XR, XW, XK, XV, XA, XG);
    // big projections
    gemm_nt<128, 0, false, false><<<dim3(64, 8), blk, 0, stream>>>(XR, WrB, nullptr, Rbuf, NTOK, 1024, 1024);
    gemm_nt<128, 0, false, false><<<dim3(64, 8), blk, 0, stream>>>(XK, WkB, nullptr, Kbuf, NTOK, 1024, 1024);
    gemm_nt<128, 0, false, false><<<dim3(64, 8), blk, 0, stream>>>(XV, WvB, nullptr, Vbuf, NTOK, 1024, 1024);
    // lora stage 1 (down-proj)
    gemm_nt<64, 2, false, false><<<dim3(64, 1), blk, 0, stream>>>(XW, wAB, nullptr, HW, NTOK, 64, 1024);
    gemm_nt<64, 0, false, false><<<dim3(64, 1), blk, 0, stream>>>(XA, aAB, nullptr, HA, NTOK, 64, 1024);
    gemm_nt<32, 0, false, false><<<dim3(64, 1), blk, 0, stream>>>(XV, vAB, nullptr, HV, NTOK, 32, 1024);
    gemm_nt<128, 1, false, false><<<dim3(64, 1), blk, 0, stream>>>(XG, gAB, nullptr, HG, NTOK, 128, 1024);
    // lora stage 2 (up-proj, fused epilogues); mix slots now free for reuse
    gemm_nt<128, 3, true,  true ><<<dim3(64, 8), blk, 0, stream>>>(HW, wBB, wb, Wdec, NTOK, 1024, 64);
    gemm_nt<128, 1, true,  false><<<dim3(64, 8), blk, 0, stream>>>(HA, aBB, ab, ICLR, NTOK, 1024, 64);
    gemm_nt<128, 1, true,  false><<<dim3(64, 8), blk, 0, stream>>>(HV, vBB, vb, VVb, NTOK, 1024, 32);
    gemm_nt<128, 0, false, false><<<dim3(64, 8), blk, 0, stream>>>(HG, gBB, nullptr, GATE, NTOK, 1024, 128);

    prep_kernel<<<(NTOK * Hx) / 4, blk, 0, stream>>>(Kbuf, Vbuf, ICLR, VVb, vfirst, k_k, k_a, Avec, Bvec);
    scan_kernel<<<128, blk, 0, stream>>>(Rbuf, Wdec, Kbuf, Vbuf, Avec, Bvec, Yb);
    gnorm_kernel<<<(NTOK * Hx) / 4, blk, 0, stream>>>(Yb, Rbuf, Kbuf, Vbuf, r_k, gnw, gnb, GATE);
    gemm_nt<128, 0, false, true><<<dim3(64, 8), blk, 0, stream>>>(GATE, WoB, nullptr, d_out, NTOK, 1024, 1024);
}

// Round 5
// 1765.650 us; speedup vs baseline: 2.5504x; 1.0116x over previous
//
#include <hip/hip_runtime.h>
#include <cmath>

// RWKV7 time-mixing, B=4 L=2048 D=1024 H=16 Dh=64. Inputs/outputs fp32; internal bf16 MFMA.
// Pipeline: convert-weights -> mix -> [r,k,v,lora1x4] GEMMs -> [lora2x4] GEMMs -> prep -> scan -> gnorm -> out GEMM.

#define DEV __device__ __forceinline__

typedef unsigned short u16;
typedef unsigned int u32;
typedef __bf16 bf16x8 __attribute__((ext_vector_type(8)));
typedef float f32x4 __attribute__((ext_vector_type(4)));

constexpr int Bx = 4, Lx = 2048, Dx = 1024, Hx = 16, Dh = 64;
constexpr int NTOK = Bx * Lx;       // 8192
constexpr float EPS_GN = 0.00064f;

DEV float bf2f(u16 u) { union { u32 i; float f; } c; c.i = ((u32)u) << 16; return c.f; }
DEV u16 f2bf(float f) {
    union { float f; u32 i; } c; c.f = f;
    u32 r = c.i + 0x7FFFu + ((c.i >> 16) & 1u);
    return (u16)(r >> 16);
}
DEV void unpack2(u32 u, float& a, float& b) {
    union { u32 i; float f; } c0, c1;
    c0.i = u << 16; c1.i = u & 0xFFFF0000u;
    a = c0.f; b = c1.f;
}
DEV void unpack8(const uint4& v, float* f) {
    unpack2(v.x, f[0], f[1]); unpack2(v.y, f[2], f[3]);
    unpack2(v.z, f[4], f[5]); unpack2(v.w, f[6], f[7]);
}

// ---------------- weight f32 -> bf16 conversion (12 tensors, one dispatch) ----------------
__global__ __launch_bounds__(256) void conv_kernel(
    const float* s0, const float* s1, const float* s2, const float* s3,
    const float* s4, const float* s5, const float* s6, const float* s7,
    const float* s8, const float* s9, const float* s10, const float* s11,
    u16* d0, u16* d1, u16* d2, u16* d3, u16* d4, u16* d5,
    u16* d6, u16* d7, u16* d8, u16* d9, u16* d10, u16* d11)
{
    const float* srcs[12] = {s0,s1,s2,s3,s4,s5,s6,s7,s8,s9,s10,s11};
    u16* dsts[12] = {d0,d1,d2,d3,d4,d5,d6,d7,d8,d9,d10,d11};
    const int ns[12] = {1048576,1048576,1048576,1048576,65536,65536,32768,32768,65536,65536,131072,131072};
    int t = blockIdx.y;
    int i = (blockIdx.x * 256 + threadIdx.x) * 4;
    if (i >= ns[t]) return;
    float4 v = *(const float4*)(srcs[t] + i);
    ushort4 o;
    o.x = f2bf(v.x); o.y = f2bf(v.y); o.z = f2bf(v.z); o.w = f2bf(v.w);
    *(ushort4*)(dsts[t] + i) = o;
}

// ---------------- token-shift mix: out_t = bf16(x + (x_prev - x) * mix_t) ----------------
__global__ __launch_bounds__(256) void mix_kernel(
    const float* __restrict__ x,
    const float* __restrict__ mr, const float* __restrict__ mw, const float* __restrict__ mk,
    const float* __restrict__ mv, const float* __restrict__ ma, const float* __restrict__ mg,
    u16* __restrict__ XR, u16* __restrict__ XW, u16* __restrict__ XK,
    u16* __restrict__ XV, u16* __restrict__ XA, u16* __restrict__ XG)
{
    int gi = blockIdx.x * 256 + threadIdx.x;     // 0 .. NTOK*Dx/4-1
    int n  = gi >> 8;                            // token
    int d4 = (gi & 255) << 2;                    // channel group of 4
    int l  = n & (Lx - 1);
    size_t o = (size_t)n * Dx + d4;
    float4 xc = *(const float4*)(x + o);
    float4 xp = make_float4(0.f, 0.f, 0.f, 0.f);
    if (l != 0) xp = *(const float4*)(x + o - Dx);
    float dx0 = xp.x - xc.x, dx1 = xp.y - xc.y, dx2 = xp.z - xc.z, dx3 = xp.w - xc.w;
    const float* mvs[6] = {mr, mw, mk, mv, ma, mg};
    u16* dsts[6] = {XR, XW, XK, XV, XA, XG};
#pragma unroll
    for (int j = 0; j < 6; ++j) {
        float4 m = *(const float4*)(mvs[j] + d4);
        ushort4 r;
        r.x = f2bf(fmaf(dx0, m.x, xc.x));
        r.y = f2bf(fmaf(dx1, m.y, xc.y));
        r.z = f2bf(fmaf(dx2, m.z, xc.z));
        r.w = f2bf(fmaf(dx3, m.w, xc.w));
        *(ushort4*)(dsts[j] + o) = r;
    }
}

// ---------------- bf16 MFMA GEMM, C[M,N] = act(A[M,K] . B[N,K]^T + bias_f32) ----------------
// ACT: 0 none, 1 sigmoid, 2 tanh, 3 exp(-0.606531*sigmoid)
template <int BN, int ACT, bool BIAS, bool F32OUT>
__global__ __launch_bounds__(256) void gemm_nt(
    const u16* __restrict__ A, const u16* __restrict__ Bm,
    const float* __restrict__ bias, void* __restrict__ Cv,
    int M, int N, int K)
{
    constexpr int BM = 128, BK = 32;
    constexpr int LDT = BK + 8;                    // +8 ushort pad: 80B rows, keeps 16B align
    constexpr int WGM = (BN == 128) ? 2 : 4;
    constexpr int WGN = (BN == 128) ? 2 : 1;
    constexpr int WTM = BM / WGM, WTN = BN / WGN;
    constexpr int ITM = WTM / 16, ITN = WTN / 16;
    __shared__ __align__(16) u16 Asm[BM * LDT];
    __shared__ __align__(16) u16 Bsm[BN * LDT];
    const int tid = threadIdx.x;
    const int wid = tid >> 6, lane = tid & 63;
    const int q = lane >> 4, r16 = lane & 15;
    const size_t m0 = (size_t)blockIdx.x * BM;
    const size_t n0 = (size_t)blockIdx.y * BN;
    const int wm = (wid % WGM) * WTM;
    const int wn = (wid / WGM) * WTN;
    f32x4 acc[ITM][ITN];
    const f32x4 zf = {0.f, 0.f, 0.f, 0.f};
#pragma unroll
    for (int i = 0; i < ITM; ++i)
#pragma unroll
        for (int j = 0; j < ITN; ++j) acc[i][j] = zf;

    for (int k0 = 0; k0 < K; k0 += BK) {
#pragma unroll
        for (int it = 0; it < (BM * BK) / 2048; ++it) {
            int pp = tid * 8 + it * 2048;
            int row = pp >> 5, col = pp & 31;
            *(uint4*)&Asm[row * LDT + col] = *(const uint4*)(A + (m0 + row) * K + k0 + col);
        }
        if constexpr (BN * BK >= 2048) {
#pragma unroll
            for (int it = 0; it < (BN * BK) / 2048; ++it) {
                int pp = tid * 8 + it * 2048;
                int row = pp >> 5, col = pp & 31;
                *(uint4*)&Bsm[row * LDT + col] = *(const uint4*)(Bm + (n0 + row) * K + k0 + col);
            }
        } else {
            int pp = tid * 8;
            if (pp < BN * BK) {
                int row = pp >> 5, col = pp & 31;
                *(uint4*)&Bsm[row * LDT + col] = *(const uint4*)(Bm + (n0 + row) * K + k0 + col);
            }
        }
        __syncthreads();
        bf16x8 af[ITM], bfr[ITN];
#pragma unroll
        for (int im = 0; im < ITM; ++im)
            af[im] = *(const bf16x8*)&Asm[(wm + im * 16 + r16) * LDT + q * 8];
#pragma unroll
        for (int in = 0; in < ITN; ++in)
            bfr[in] = *(const bf16x8*)&Bsm[(wn + in * 16 + r16) * LDT + q * 8];
#pragma unroll
        for (int im = 0; im < ITM; ++im)
#pragma unroll
            for (int in = 0; in < ITN; ++in)
                acc[im][in] = __builtin_amdgcn_mfma_f32_16x16x32_bf16(af[im], bfr[in], acc[im][in], 0, 0, 0);
        __syncthreads();
    }
    // epilogue: C/D layout col = lane&15 (n), row = quad*4+reg (m)  [m89-verified]
#pragma unroll
    for (int im = 0; im < ITM; ++im) {
#pragma unroll
        for (int in = 0; in < ITN; ++in) {
#pragma unroll
            for (int e = 0; e < 4; ++e) {
                size_t row = m0 + wm + im * 16 + q * 4 + e;
                size_t col = n0 + wn + in * 16 + r16;
                float val = acc[im][in][e];
                if constexpr (BIAS) val += bias[col];
                if constexpr (ACT == 1) val = 1.f / (1.f + __expf(-val));
                else if constexpr (ACT == 2) val = tanhf(val);
                else if constexpr (ACT == 3) val = __expf(-0.606531f / (1.f + __expf(-val)));
                if constexpr (F32OUT) ((float*)Cv)[row * (size_t)N + col] = val;
                else ((u16*)Cv)[row * (size_t)N + col] = f2bf(val);
            }
        }
    }
}

// ---------------- prep: kk-normalize, a/b vectors, k/v updates ----------------
__global__ __launch_bounds__(256) void prep_kernel(
    u16* __restrict__ Kb, u16* __restrict__ Vb,
    const u16* __restrict__ ICLR, const u16* __restrict__ VVb, const float* __restrict__ vfirst,
    const float* __restrict__ k_k, const float* __restrict__ k_a,
    u16* __restrict__ Av, u16* __restrict__ Bv)
{
    int g = blockIdx.x * 4 + (threadIdx.x >> 6);   // (token,head) pair
    int lane = threadIdx.x & 63;
    int h = g & (Hx - 1);
    size_t idx = (size_t)g * 64 + lane;            // == n*1024 + h*64 + lane
    int hd = h * 64 + lane;
    float k = bf2f(Kb[idx]);
    float iclr = bf2f(ICLR[idx]);
    float kkn = k * k_k[hd];
    float s = kkn * kkn;
#pragma unroll
    for (int off = 32; off > 0; off >>= 1) s += __shfl_xor(s, off, 64);
    float nrm = fmaxf(sqrtf(s), 1e-7f);
    float kk = kkn / nrm;
    Av[idx] = f2bf(-kk);
    Bv[idx] = f2bf(kk * iclr);
    Kb[idx] = f2bf(k * (1.f + (iclr - 1.f) * k_a[hd]));
    float v = bf2f(Vb[idx]), vv = bf2f(VVb[idx]), vf = vfirst[idx];
    Vb[idx] = f2bf(fmaf(vf - v, vv, v));
}

// ---------------- WKV7 scan v4: wave-local, barrier-free, 4-deep prefetch ----------------
// 8 single-wave blocks per (b,h); wave owns 8 rows x 64 cols.
// Lane: cg = lane&7 (col group, cols [8cg,8cg+8)), rowidx = lane>>3, row = 8*widx + rowidx.
// S[8]/thread. sa & y reductions via shfl_xor(1,2,4) - within 32-lane halves (ds_swizzle).
struct SBuf { uint4 r, k, a, b; float4 w0, w1; float v; };

DEV void scan_load(SBuf& s, const u16* Rb, const float* Wd, const u16* Kb,
                   const u16* Vb, const u16* Av, const u16* Bv,
                   size_t vecoff, size_t voff)
{
    s.r = *(const uint4*)(Rb + vecoff);
    s.k = *(const uint4*)(Kb + vecoff);
    s.a = *(const uint4*)(Av + vecoff);
    s.b = *(const uint4*)(Bv + vecoff);
    s.w0 = *(const float4*)(Wd + vecoff);
    s.w1 = *(const float4*)(Wd + vecoff + 4);
    s.v = bf2f(Vb[voff]);
}

DEV void scan_step(float* S, const SBuf& sb, float* Yp, int cg)
{
    float r[8], k[8], a[8], b[8];
    unpack8(sb.r, r); unpack8(sb.k, k); unpack8(sb.a, a); unpack8(sb.b, b);
    const float w[8] = {sb.w0.x, sb.w0.y, sb.w0.z, sb.w0.w,
                        sb.w1.x, sb.w1.y, sb.w1.z, sb.w1.w};
    float sa0 = 0.f, sa1 = 0.f;
#pragma unroll
    for (int c = 0; c < 8; c += 2) {
        sa0 = fmaf(S[c], a[c], sa0);
        sa1 = fmaf(S[c + 1], a[c + 1], sa1);
    }
    float sa = sa0 + sa1;
    sa += __shfl_xor(sa, 1, 64);
    sa += __shfl_xor(sa, 2, 64);
    sa += __shfl_xor(sa, 4, 64);
    float y0 = 0.f, y1 = 0.f;
#pragma unroll
    for (int c = 0; c < 8; c += 2) {
        float s0 = fmaf(S[c], w[c], fmaf(sb.v, k[c], sa * b[c]));
        float s1 = fmaf(S[c + 1], w[c + 1], fmaf(sb.v, k[c + 1], sa * b[c + 1]));
        S[c] = s0; S[c + 1] = s1;
        y0 = fmaf(s0, r[c], y0);
        y1 = fmaf(s1, r[c + 1], y1);
    }
    float y = y0 + y1;
    y += __shfl_xor(y, 1, 64);
    y += __shfl_xor(y, 2, 64);
    y += __shfl_xor(y, 4, 64);
    if (cg == 0) *Yp = y;
}

__global__ __launch_bounds__(64, 1) void scan_kernel(
    const u16* __restrict__ Rb, const float* __restrict__ Wd,
    const u16* __restrict__ Kb, const u16* __restrict__ Vb,
    const u16* __restrict__ Av, const u16* __restrict__ Bv,
    float* __restrict__ Y)
{
    const int blk = blockIdx.x;                   // 0..511
    const int bh = blk >> 3;                      // b*16+h
    const int widx = blk & 7;                     // row-group of this wave
    const int lane = threadIdx.x;
    const int cg = lane & 7, rowidx = lane >> 3;
    const int row = widx * 8 + rowidx;
    const int col0 = cg * 8;
    const size_t base = (size_t)(bh >> 4) * ((size_t)Lx * Dx) + (size_t)(bh & 15) * 64;
    const size_t vec0 = base + col0;
    const size_t v0 = base + row;

    float S[8];
#pragma unroll
    for (int c = 0; c < 8; ++c) S[c] = 0.f;

    SBuf buf[4];
#pragma unroll
    for (int i = 0; i < 4; ++i)
        scan_load(buf[i], Rb, Wd, Kb, Vb, Av, Bv,
                  vec0 + (size_t)i * Dx, v0 + (size_t)i * Dx);

    for (int t = 0; t < Lx; t += 4) {
#pragma unroll
        for (int u = 0; u < 4; ++u) {
            scan_step(S, buf[u], Y + base + (size_t)(t + u) * Dx + row, cg);
            if (t + u + 4 < Lx)
                scan_load(buf[u], Rb, Wd, Kb, Vb, Av, Bv,
                          vec0 + (size_t)(t + u + 4) * Dx, v0 + (size_t)(t + u + 4) * Dx);
        }
    }
}

// ---------------- group-norm + rkr residual + gate (OG written in-place over GATE) ----------------
__global__ __launch_bounds__(256) void gnorm_kernel(
    const float* __restrict__ Y, const u16* __restrict__ Rb, const u16* __restrict__ Kb,
    const u16* __restrict__ Vb, const float* __restrict__ r_k,
    const float* __restrict__ gnw, const float* __restrict__ gnb,
    u16* __restrict__ GATE_OG)
{
    int g = blockIdx.x * 4 + (threadIdx.x >> 6);
    int lane = threadIdx.x & 63;
    int h = g & (Hx - 1);
    size_t idx = (size_t)g * 64 + lane;
    int hd = h * 64 + lane;
    float y = Y[idx];
    float r = bf2f(Rb[idx]), k = bf2f(Kb[idx]), v = bf2f(Vb[idx]);
    float rkr = r * k * r_k[hd];
    float s1 = y, s2 = y * y, s3 = rkr;
#pragma unroll
    for (int off = 32; off > 0; off >>= 1) {
        s1 += __shfl_xor(s1, off, 64);
        s2 += __shfl_xor(s2, off, 64);
        s3 += __shfl_xor(s3, off, 64);
    }
    float mean = s1 * (1.f / 64.f);
    float var  = s2 * (1.f / 64.f) - mean * mean;
    float inv = 1.f / sqrtf(var + EPS_GN);
    float o = gnw[hd] * ((y - mean) * inv) + gnb[hd];
    o += s3 * v;
    GATE_OG[idx] = f2bf(o * bf2f(GATE_OG[idx]));
}

// ---------------- launch ----------------
extern "C" void kernel_launch(void* const* d_in, const int* in_sizes, int n_in,
                              void* d_out, int out_size, void* d_ws, size_t ws_size,
                              hipStream_t stream)
{
    const float* x      = (const float*)d_in[0];
    const float* vfirst = (const float*)d_in[1];
    const float* x_r = (const float*)d_in[2];
    const float* x_w = (const float*)d_in[3];
    const float* x_k = (const float*)d_in[4];
    const float* x_v = (const float*)d_in[5];
    const float* x_a = (const float*)d_in[6];
    const float* x_g = (const float*)d_in[7];
    const float* k_k = (const float*)d_in[8];
    const float* k_a = (const float*)d_in[9];
    const float* r_k = (const float*)d_in[10];
    const float* Wr  = (const float*)d_in[11];
    const float* Wk  = (const float*)d_in[12];
    const float* Wv  = (const float*)d_in[13];
    const float* Wo  = (const float*)d_in[14];
    const float* gnw = (const float*)d_in[15];
    const float* gnb = (const float*)d_in[16];
    const float* wA  = (const float*)d_in[17];
    const float* wB  = (const float*)d_in[18];
    const float* wb  = (const float*)d_in[19];
    const float* vA  = (const float*)d_in[20];
    const float* vB  = (const float*)d_in[21];
    const float* vb  = (const float*)d_in[22];
    const float* aA  = (const float*)d_in[23];
    const float* aB  = (const float*)d_in[24];
    const float* ab  = (const float*)d_in[25];
    const float* gA  = (const float*)d_in[26];
    const float* gB  = (const float*)d_in[27];

    char* ws = (char*)d_ws;
    const size_t SLOT = (size_t)NTOK * Dx * 2;   // 16 MiB; 14 slots (~224 MiB)
    u16* XR = (u16*)(ws + 0 * SLOT);
    u16* XW = (u16*)(ws + 1 * SLOT);
    u16* XK = (u16*)(ws + 2 * SLOT);
    u16* XV = (u16*)(ws + 3 * SLOT);
    u16* XA = (u16*)(ws + 4 * SLOT);
    u16* XG = (u16*)(ws + 5 * SLOT);
    u16* Rbuf = (u16*)(ws + 6 * SLOT);
    u16* Kbuf = (u16*)(ws + 7 * SLOT);
    u16* Vbuf = (u16*)(ws + 8 * SLOT);
    u16* HW = (u16*)(ws + 9 * SLOT);             // slot 9 holds all 4 lora hiddens
    u16* HA = HW + (size_t)NTOK * 64;
    u16* HV = HA + (size_t)NTOK * 64;
    u16* HG = HV + (size_t)NTOK * 32;
    u16* Bvec = (u16*)(ws + 10 * SLOT);
    float* Yb = (float*)(ws + 11 * SLOT);        // slots 11-12 (fp32)
    // slot 13: converted bf16 weights (~9.2 MiB used)
    u16* WrB = (u16*)(ws + 13 * SLOT);
    u16* WkB = WrB + 1048576;
    u16* WvB = WkB + 1048576;
    u16* WoB = WvB + 1048576;
    u16* wAB = WoB + 1048576;
    u16* wBB = wAB + 65536;
    u16* vAB = wBB + 65536;
    u16* vBB = vAB + 32768;
    u16* aAB = vBB + 32768;
    u16* aBB = aAB + 65536;
    u16* gAB = aBB + 65536;
    u16* gBB = gAB + 131072;
    // reuse of consumed mix slots:
    float* Wdec = (float*)(ws + 0 * SLOT);       // slots 0-1 (fp32 decay)
    u16* ICLR = (u16*)(ws + 2 * SLOT);
    u16* VVb  = (u16*)(ws + 3 * SLOT);
    u16* GATE = (u16*)(ws + 4 * SLOT);           // gnorm writes OG in-place here
    u16* Avec = (u16*)(ws + 5 * SLOT);

    dim3 blk(256);
    conv_kernel<<<dim3(1024, 12), blk, 0, stream>>>(Wr, Wk, Wv, Wo, wA, wB, vA, vB, aA, aB, gA, gB,
                                                    WrB, WkB, WvB, WoB, wAB, wBB, vAB, vBB, aAB, aBB, gAB, gBB);
    mix_kernel<<<(NTOK * Dx / 4) / 256, blk, 0, stream>>>(x, x_r, x_w, x_k, x_v, x_a, x_g,
                                                          XR, XW, XK, XV, XA, XG);
    // big projections
    gemm_nt<128, 0, false, false><<<dim3(64, 8), blk, 0, stream>>>(XR, WrB, nullptr, Rbuf, NTOK, 1024, 1024);
    gemm_nt<128, 0, false, false><<<dim3(64, 8), blk, 0, stream>>>(XK, WkB, nullptr, Kbuf, NTOK, 1024, 1024);
    gemm_nt<128, 0, false, false><<<dim3(64, 8), blk, 0, stream>>>(XV, WvB, nullptr, Vbuf, NTOK, 1024, 1024);
    // lora stage 1 (down-proj)
    gemm_nt<64, 2, false, false><<<dim3(64, 1), blk, 0, stream>>>(XW, wAB, nullptr, HW, NTOK, 64, 1024);
    gemm_nt<64, 0, false, false><<<dim3(64, 1), blk, 0, stream>>>(XA, aAB, nullptr, HA, NTOK, 64, 1024);
    gemm_nt<32, 0, false, false><<<dim3(64, 1), blk, 0, stream>>>(XV, vAB, nullptr, HV, NTOK, 32, 1024);
    gemm_nt<128, 1, false, false><<<dim3(64, 1), blk, 0, stream>>>(XG, gAB, nullptr, HG, NTOK, 128, 1024);
    // lora stage 2 (up-proj, fused epilogues); mix slots now free for reuse
    gemm_nt<128, 3, true,  true ><<<dim3(64, 8), blk, 0, stream>>>(HW, wBB, wb, Wdec, NTOK, 1024, 64);
    gemm_nt<128, 1, true,  false><<<dim3(64, 8), blk, 0, stream>>>(HA, aBB, ab, ICLR, NTOK, 1024, 64);
    gemm_nt<128, 1, true,  false><<<dim3(64, 8), blk, 0, stream>>>(HV, vBB, vb, VVb, NTOK, 1024, 32);
    gemm_nt<128, 0, false, false><<<dim3(64, 8), blk, 0, stream>>>(HG, gBB, nullptr, GATE, NTOK, 1024, 128);

    prep_kernel<<<(NTOK * Hx) / 4, blk, 0, stream>>>(Kbuf, Vbuf, ICLR, VVb, vfirst, k_k, k_a, Avec, Bvec);
    scan_kernel<<<512, 64, 0, stream>>>(Rbuf, Wdec, Kbuf, Vbuf, Avec, Bvec, Yb);
    gnorm_kernel<<<(NTOK * Hx) / 4, blk, 0, stream>>>(Yb, Rbuf, Kbuf, Vbuf, r_k, gnw, gnb, GATE);
    gemm_nt<128, 0, false, true><<<dim3(64, 8), blk, 0, stream>>>(GATE, WoB, nullptr, d_out, NTOK, 1024, 1024);
}

// Round 6
// 1338.417 us; speedup vs baseline: 3.3646x; 1.3192x over previous
//
#include <hip/hip_runtime.h>
#include <cmath>

// RWKV7 time-mixing, B=4 L=2048 D=1024 H=16 Dh=64. Inputs/outputs fp32; internal bf16.
// convert(lora wts) -> mix -> [r,k,v (B=f32)] + lora1 -> lora2 -> prep_pack(stream) ->
// scan (LDS double-buffered global_load_lds batches) -> gnorm -> out GEMM.

#define DEV __device__ __forceinline__

typedef unsigned short u16;
typedef unsigned int u32;
typedef __bf16 bf16x8 __attribute__((ext_vector_type(8)));
typedef float f32x4 __attribute__((ext_vector_type(4)));

constexpr int Bx = 4, Lx = 2048, Dx = 1024, Hx = 16, Dh = 64;
constexpr int NTOK = Bx * Lx;       // 8192
constexpr float EPS_GN = 0.00064f;
constexpr int STEP_U16 = 384;       // 768B per step: r|k|a|b|v|w (64 bf16 each)
constexpr int TB = 16;              // steps per scan batch
constexpr int NB = Lx / TB;         // 128 batches
constexpr int BATCH_U16 = TB * STEP_U16;   // 6144 u16 = 12288 B

DEV float bf2f(u16 u) { union { u32 i; float f; } c; c.i = ((u32)u) << 16; return c.f; }
DEV u16 f2bf(float f) {
    union { float f; u32 i; } c; c.f = f;
    u32 r = c.i + 0x7FFFu + ((c.i >> 16) & 1u);
    return (u16)(r >> 16);
}
DEV void unpack2(u32 u, float& a, float& b) {
    union { u32 i; float f; } c0, c1;
    c0.i = u << 16; c1.i = u & 0xFFFF0000u;
    a = c0.f; b = c1.f;
}
DEV void unpack8(const uint4& v, float* f) {
    unpack2(v.x, f[0], f[1]); unpack2(v.y, f[2], f[3]);
    unpack2(v.z, f[4], f[5]); unpack2(v.w, f[6], f[7]);
}

// ---------------- lora-weight f32 -> bf16 conversion (8 small tensors) ----------------
__global__ __launch_bounds__(256) void conv_kernel(
    const float* s0, const float* s1, const float* s2, const float* s3,
    const float* s4, const float* s5, const float* s6, const float* s7,
    u16* d0, u16* d1, u16* d2, u16* d3, u16* d4, u16* d5, u16* d6, u16* d7)
{
    const float* srcs[8] = {s0,s1,s2,s3,s4,s5,s6,s7};
    u16* dsts[8] = {d0,d1,d2,d3,d4,d5,d6,d7};
    const int ns[8] = {65536,65536,32768,32768,65536,65536,131072,131072};
    int t = blockIdx.y;
    int i = (blockIdx.x * 256 + threadIdx.x) * 4;
    if (i >= ns[t]) return;
    float4 v = *(const float4*)(srcs[t] + i);
    ushort4 o;
    o.x = f2bf(v.x); o.y = f2bf(v.y); o.z = f2bf(v.z); o.w = f2bf(v.w);
    *(ushort4*)(dsts[t] + i) = o;
}

// ---------------- token-shift mix ----------------
__global__ __launch_bounds__(256) void mix_kernel(
    const float* __restrict__ x,
    const float* __restrict__ mr, const float* __restrict__ mw, const float* __restrict__ mk,
    const float* __restrict__ mv, const float* __restrict__ ma, const float* __restrict__ mg,
    u16* __restrict__ XR, u16* __restrict__ XW, u16* __restrict__ XK,
    u16* __restrict__ XV, u16* __restrict__ XA, u16* __restrict__ XG)
{
    int gi = blockIdx.x * 256 + threadIdx.x;
    int n  = gi >> 8;
    int d4 = (gi & 255) << 2;
    int l  = n & (Lx - 1);
    size_t o = (size_t)n * Dx + d4;
    float4 xc = *(const float4*)(x + o);
    float4 xp = make_float4(0.f, 0.f, 0.f, 0.f);
    if (l != 0) xp = *(const float4*)(x + o - Dx);
    float dx0 = xp.x - xc.x, dx1 = xp.y - xc.y, dx2 = xp.z - xc.z, dx3 = xp.w - xc.w;
    const float* mvs[6] = {mr, mw, mk, mv, ma, mg};
    u16* dsts[6] = {XR, XW, XK, XV, XA, XG};
#pragma unroll
    for (int j = 0; j < 6; ++j) {
        float4 m = *(const float4*)(mvs[j] + d4);
        ushort4 r;
        r.x = f2bf(fmaf(dx0, m.x, xc.x));
        r.y = f2bf(fmaf(dx1, m.y, xc.y));
        r.z = f2bf(fmaf(dx2, m.z, xc.z));
        r.w = f2bf(fmaf(dx3, m.w, xc.w));
        *(ushort4*)(dsts[j] + o) = r;
    }
}

// ---------------- bf16 MFMA GEMM, C[M,N] = act(A[M,K] . B[N,K]^T + bias_f32) ----------------
// ACT: 0 none, 1 sigmoid, 2 tanh, 3 exp(-0.606531*sigmoid). BF32: B matrix is f32 (converted in staging).
template <int BN, int ACT, bool BIAS, bool F32OUT, bool BF32>
__global__ __launch_bounds__(256) void gemm_nt(
    const u16* __restrict__ A, const void* __restrict__ Bmv,
    const float* __restrict__ bias, void* __restrict__ Cv,
    int M, int N, int K)
{
    constexpr int BM = 128, BK = 32;
    constexpr int LDT = BK + 8;
    constexpr int WGM = (BN == 128) ? 2 : 4;
    constexpr int WGN = (BN == 128) ? 2 : 1;
    constexpr int WTM = BM / WGM, WTN = BN / WGN;
    constexpr int ITM = WTM / 16, ITN = WTN / 16;
    __shared__ __align__(16) u16 Asm[BM * LDT];
    __shared__ __align__(16) u16 Bsm[BN * LDT];
    const int tid = threadIdx.x;
    const int wid = tid >> 6, lane = tid & 63;
    const int q = lane >> 4, r16 = lane & 15;
    const size_t m0 = (size_t)blockIdx.x * BM;
    const size_t n0 = (size_t)blockIdx.y * BN;
    const int wm = (wid % WGM) * WTM;
    const int wn = (wid / WGM) * WTN;
    f32x4 acc[ITM][ITN];
    const f32x4 zf = {0.f, 0.f, 0.f, 0.f};
#pragma unroll
    for (int i = 0; i < ITM; ++i)
#pragma unroll
        for (int j = 0; j < ITN; ++j) acc[i][j] = zf;

    const u16* B16 = (const u16*)Bmv;
    const float* B32 = (const float*)Bmv;

    for (int k0 = 0; k0 < K; k0 += BK) {
#pragma unroll
        for (int it = 0; it < (BM * BK) / 2048; ++it) {
            int pp = tid * 8 + it * 2048;
            int row = pp >> 5, col = pp & 31;
            *(uint4*)&Asm[row * LDT + col] = *(const uint4*)(A + (m0 + row) * K + k0 + col);
        }
#pragma unroll
        for (int it = 0; it < (BN * BK + 2047) / 2048; ++it) {
            int pp = tid * 8 + it * 2048;
            if (BN * BK >= 2048 || pp < BN * BK) {
                int row = pp >> 5, col = pp & 31;
                if constexpr (BF32) {
                    float4 f0 = *(const float4*)(B32 + (n0 + row) * K + k0 + col);
                    float4 f1 = *(const float4*)(B32 + (n0 + row) * K + k0 + col + 4);
                    ushort4 o0, o1;
                    o0.x = f2bf(f0.x); o0.y = f2bf(f0.y); o0.z = f2bf(f0.z); o0.w = f2bf(f0.w);
                    o1.x = f2bf(f1.x); o1.y = f2bf(f1.y); o1.z = f2bf(f1.z); o1.w = f2bf(f1.w);
                    *(ushort4*)&Bsm[row * LDT + col] = o0;
                    *(ushort4*)&Bsm[row * LDT + col + 4] = o1;
                } else {
                    *(uint4*)&Bsm[row * LDT + col] = *(const uint4*)(B16 + (n0 + row) * K + k0 + col);
                }
            }
        }
        __syncthreads();
        bf16x8 af[ITM], bfr[ITN];
#pragma unroll
        for (int im = 0; im < ITM; ++im)
            af[im] = *(const bf16x8*)&Asm[(wm + im * 16 + r16) * LDT + q * 8];
#pragma unroll
        for (int in = 0; in < ITN; ++in)
            bfr[in] = *(const bf16x8*)&Bsm[(wn + in * 16 + r16) * LDT + q * 8];
#pragma unroll
        for (int im = 0; im < ITM; ++im)
#pragma unroll
            for (int in = 0; in < ITN; ++in)
                acc[im][in] = __builtin_amdgcn_mfma_f32_16x16x32_bf16(af[im], bfr[in], acc[im][in], 0, 0, 0);
        __syncthreads();
    }
#pragma unroll
    for (int im = 0; im < ITM; ++im) {
#pragma unroll
        for (int in = 0; in < ITN; ++in) {
#pragma unroll
            for (int e = 0; e < 4; ++e) {
                size_t row = m0 + wm + im * 16 + q * 4 + e;
                size_t col = n0 + wn + in * 16 + r16;
                float val = acc[im][in][e];
                if constexpr (BIAS) val += bias[col];
                if constexpr (ACT == 1) val = 1.f / (1.f + __expf(-val));
                else if constexpr (ACT == 2) val = tanhf(val);
                else if constexpr (ACT == 3) val = __expf(-0.606531f / (1.f + __expf(-val)));
                if constexpr (F32OUT) ((float*)Cv)[row * (size_t)N + col] = val;
                else ((u16*)Cv)[row * (size_t)N + col] = f2bf(val);
            }
        }
    }
}

// ---------------- prep + pack: kk-norm, a/b, k/v updates, emit packed stream ----------------
__global__ __launch_bounds__(256) void prep_pack_kernel(
    u16* __restrict__ Kb, u16* __restrict__ Vb,
    const u16* __restrict__ Rb, const u16* __restrict__ Wd16,
    const u16* __restrict__ ICLR, const u16* __restrict__ VVb, const float* __restrict__ vfirst,
    const float* __restrict__ k_k, const float* __restrict__ k_a,
    u16* __restrict__ stream)
{
    int g = blockIdx.x * 4 + (threadIdx.x >> 6);   // (token,head) pair: n = g>>4, h = g&15
    int lane = threadIdx.x & 63;
    int h = g & (Hx - 1);
    int n = g >> 4;
    size_t idx = (size_t)g * 64 + lane;            // == n*1024 + h*64 + lane
    int hd = h * 64 + lane;
    int l = n & (Lx - 1), b = n >> 11;
    size_t so = ((size_t)((b * 16 + h) * Lx + l)) * STEP_U16;

    float k = bf2f(Kb[idx]);
    float iclr = bf2f(ICLR[idx]);
    float kkn = k * k_k[hd];
    float s = kkn * kkn;
#pragma unroll
    for (int off = 32; off > 0; off >>= 1) s += __shfl_xor(s, off, 64);
    float nrm = fmaxf(sqrtf(s), 1e-7f);
    float kk = kkn / nrm;
    u16 knew = f2bf(k * (1.f + (iclr - 1.f) * k_a[hd]));
    float v = bf2f(Vb[idx]), vv = bf2f(VVb[idx]), vf = vfirst[idx];
    u16 vnew = f2bf(fmaf(vf - v, vv, v));
    Kb[idx] = knew;
    Vb[idx] = vnew;
    stream[so + lane]       = Rb[idx];
    stream[so + 64 + lane]  = knew;
    stream[so + 128 + lane] = f2bf(-kk);
    stream[so + 192 + lane] = f2bf(kk * iclr);
    stream[so + 256 + lane] = vnew;
    stream[so + 320 + lane] = Wd16[idx];
}

// ---------------- WKV7 scan v5: LDS double-buffered batches via global_load_lds ----------------
// 2 blocks per (b,h) (row halves); 4 waves/block, wave owns 8 rows; lane: cg=lane&7 (cols 8cg..),
// rowidx=lane>>3. S[8]/thread. Reductions shfl_xor(1,2,4). Batches of 16 steps staged async.
__global__ __launch_bounds__(256, 1) void scan_kernel(
    const u16* __restrict__ stream, float* __restrict__ Y)
{
    const int blk = blockIdx.x;                   // 0..127
    const int bh = blk >> 1;
    const int rh = blk & 1;
    const int tid = threadIdx.x;
    const int lane = tid & 63;
    const int w = tid >> 6;
    const int cg = lane & 7, rowidx = lane >> 3;
    const int lr = w * 8 + rowidx;                // local row 0..31
    const int row = rh * 32 + lr;                 // global row 0..63
    const size_t sbase = (size_t)bh * Lx * STEP_U16;
    const size_t ybase = (size_t)(bh >> 4) * ((size_t)Lx * Dx) + (size_t)(bh & 15) * 64;

    __shared__ __align__(16) u16 sbuf[2 * BATCH_U16];   // 24 KB
    __shared__ __align__(16) float ylds[TB * 32];       // 2 KB

    float S[8];
#pragma unroll
    for (int c = 0; c < 8; ++c) S[c] = 0.f;

    // stage batch 0 into buf 0 (wave w handles 1KB chunks 3w..3w+2)
    {
        const u16* g = stream + sbase;
#pragma unroll
        for (int c = 0; c < 3; ++c) {
            const u16* gp = g + (3 * w + c) * 512 + lane * 8;
            u16* lp = sbuf + (3 * w + c) * 512;
            __builtin_amdgcn_global_load_lds(
                (const __attribute__((address_space(1))) void*)gp,
                (__attribute__((address_space(3))) void*)lp, 16, 0, 0);
        }
    }

    for (int bt = 0; bt < NB; ++bt) {
        const int cur = bt & 1;
        __syncthreads();   // vmcnt(0): batch bt resident; ylds free from prev flush
        if (bt + 1 < NB) {
            const u16* g = stream + sbase + (size_t)(bt + 1) * BATCH_U16;
            u16* lbase = sbuf + (1 - cur) * BATCH_U16;
#pragma unroll
            for (int c = 0; c < 3; ++c) {
                const u16* gp = g + (3 * w + c) * 512 + lane * 8;
                u16* lp = lbase + (3 * w + c) * 512;
                __builtin_amdgcn_global_load_lds(
                    (const __attribute__((address_space(1))) void*)gp,
                    (__attribute__((address_space(3))) void*)lp, 16, 0, 0);
            }
        }
        const u16* bp = sbuf + cur * BATCH_U16;
#pragma unroll 4
        for (int s = 0; s < TB; ++s) {
            const u16* sp = bp + s * STEP_U16;
            uint4 r4 = *(const uint4*)(sp + cg * 8);
            uint4 k4 = *(const uint4*)(sp + 64 + cg * 8);
            uint4 a4 = *(const uint4*)(sp + 128 + cg * 8);
            uint4 b4 = *(const uint4*)(sp + 192 + cg * 8);
            float v  = bf2f(sp[256 + row]);
            uint4 w4 = *(const uint4*)(sp + 320 + cg * 8);
            float rr[8], kk[8], aa[8], bb[8], ww[8];
            unpack8(r4, rr); unpack8(k4, kk); unpack8(a4, aa); unpack8(b4, bb); unpack8(w4, ww);
            float sa0 = 0.f, sa1 = 0.f;
#pragma unroll
            for (int c = 0; c < 8; c += 2) {
                sa0 = fmaf(S[c], aa[c], sa0);
                sa1 = fmaf(S[c + 1], aa[c + 1], sa1);
            }
            float sa = sa0 + sa1;
            sa += __shfl_xor(sa, 1, 64);
            sa += __shfl_xor(sa, 2, 64);
            sa += __shfl_xor(sa, 4, 64);
            float y0 = 0.f, y1 = 0.f;
#pragma unroll
            for (int c = 0; c < 8; c += 2) {
                float s0 = fmaf(S[c], ww[c], fmaf(v, kk[c], sa * bb[c]));
                float s1 = fmaf(S[c + 1], ww[c + 1], fmaf(v, kk[c + 1], sa * bb[c + 1]));
                S[c] = s0; S[c + 1] = s1;
                y0 = fmaf(s0, rr[c], y0);
                y1 = fmaf(s1, rr[c + 1], y1);
            }
            float y = y0 + y1;
            y += __shfl_xor(y, 1, 64);
            y += __shfl_xor(y, 2, 64);
            y += __shfl_xor(y, 4, 64);
            if (cg == 0) ylds[s * 32 + lr] = y;
        }
        __syncthreads();   // ylds visible; batch bt+1 loads drained (issued ~16 steps ago)
        // coalesced flush: 256 threads x 2 floats = 512 = 16 steps x 32 rows
        {
            int idx2 = tid * 2;
            int s = idx2 >> 5, j = idx2 & 31;
            float2 val = *(const float2*)(&ylds[s * 32 + j]);
            *(float2*)(Y + ybase + (size_t)(bt * TB + s) * Dx + rh * 32 + j) = val;
        }
    }
}

// ---------------- group-norm + rkr residual + gate (OG in-place over GATE) ----------------
__global__ __launch_bounds__(256) void gnorm_kernel(
    const float* __restrict__ Y, const u16* __restrict__ Rb, const u16* __restrict__ Kb,
    const u16* __restrict__ Vb, const float* __restrict__ r_k,
    const float* __restrict__ gnw, const float* __restrict__ gnb,
    u16* __restrict__ GATE_OG)
{
    int g = blockIdx.x * 4 + (threadIdx.x >> 6);
    int lane = threadIdx.x & 63;
    int h = g & (Hx - 1);
    size_t idx = (size_t)g * 64 + lane;
    int hd = h * 64 + lane;
    float y = Y[idx];
    float r = bf2f(Rb[idx]), k = bf2f(Kb[idx]), v = bf2f(Vb[idx]);
    float rkr = r * k * r_k[hd];
    float s1 = y, s2 = y * y, s3 = rkr;
#pragma unroll
    for (int off = 32; off > 0; off >>= 1) {
        s1 += __shfl_xor(s1, off, 64);
        s2 += __shfl_xor(s2, off, 64);
        s3 += __shfl_xor(s3, off, 64);
    }
    float mean = s1 * (1.f / 64.f);
    float var  = s2 * (1.f / 64.f) - mean * mean;
    float inv = 1.f / sqrtf(var + EPS_GN);
    float o = gnw[hd] * ((y - mean) * inv) + gnb[hd];
    o += s3 * v;
    GATE_OG[idx] = f2bf(o * bf2f(GATE_OG[idx]));
}

// ---------------- launch ----------------
extern "C" void kernel_launch(void* const* d_in, const int* in_sizes, int n_in,
                              void* d_out, int out_size, void* d_ws, size_t ws_size,
                              hipStream_t stream_)
{
    const float* x      = (const float*)d_in[0];
    const float* vfirst = (const float*)d_in[1];
    const float* x_r = (const float*)d_in[2];
    const float* x_w = (const float*)d_in[3];
    const float* x_k = (const float*)d_in[4];
    const float* x_v = (const float*)d_in[5];
    const float* x_a = (const float*)d_in[6];
    const float* x_g = (const float*)d_in[7];
    const float* k_k = (const float*)d_in[8];
    const float* k_a = (const float*)d_in[9];
    const float* r_k = (const float*)d_in[10];
    const float* Wr  = (const float*)d_in[11];
    const float* Wk  = (const float*)d_in[12];
    const float* Wv  = (const float*)d_in[13];
    const float* Wo  = (const float*)d_in[14];
    const float* gnw = (const float*)d_in[15];
    const float* gnb = (const float*)d_in[16];
    const float* wA  = (const float*)d_in[17];
    const float* wB  = (const float*)d_in[18];
    const float* wb  = (const float*)d_in[19];
    const float* vA  = (const float*)d_in[20];
    const float* vB  = (const float*)d_in[21];
    const float* vb  = (const float*)d_in[22];
    const float* aA  = (const float*)d_in[23];
    const float* aB  = (const float*)d_in[24];
    const float* ab  = (const float*)d_in[25];
    const float* gA  = (const float*)d_in[26];
    const float* gB  = (const float*)d_in[27];

    char* ws = (char*)d_ws;
    const size_t SLOT = (size_t)NTOK * Dx * 2;   // 16 MiB; 14 slots total (224 MiB, proven)
    u16* XR = (u16*)(ws + 0 * SLOT);
    u16* XW = (u16*)(ws + 1 * SLOT);
    u16* XK = (u16*)(ws + 2 * SLOT);
    u16* XV = (u16*)(ws + 3 * SLOT);
    u16* XA = (u16*)(ws + 4 * SLOT);
    u16* XG = (u16*)(ws + 5 * SLOT);
    u16* STREAM = (u16*)(ws + 0 * SLOT);         // 96MB, overwrites XR..XG after consumption
    u16* Rbuf = (u16*)(ws + 6 * SLOT);
    u16* Kbuf = (u16*)(ws + 7 * SLOT);
    u16* Vbuf = (u16*)(ws + 8 * SLOT);
    u16* HW = (u16*)(ws + 9 * SLOT);             // lora hiddens (4.7MB)
    u16* HA = HW + (size_t)NTOK * 64;
    u16* HV = HA + (size_t)NTOK * 64;
    u16* HG = HV + (size_t)NTOK * 32;
    u16* SW = (u16*)(ws + 9 * SLOT + 8 * 1024 * 1024);  // small bf16 weights (1.2MB)
    u16* wAB = SW;
    u16* wBB = wAB + 65536;
    u16* vAB = wBB + 65536;
    u16* vBB = vAB + 32768;
    u16* aAB = vBB + 32768;
    u16* aBB = aAB + 65536;
    u16* gAB = aBB + 65536;
    u16* gBB = gAB + 131072;
    u16* Wdec16 = (u16*)(ws + 10 * SLOT);        // bf16 decay; dead after prep_pack
    u16* ICLR   = (u16*)(ws + 11 * SLOT);        // dead after prep_pack
    u16* VVb    = (u16*)(ws + 12 * SLOT);        // dead after prep_pack
    float* Yb   = (float*)(ws + 10 * SLOT);      // fp32, slots 10-11 (aliases Wdec16/ICLR, ordered)
    u16* GATE   = (u16*)(ws + 13 * SLOT);        // gnorm writes OG in-place

    dim3 blk(256);
    conv_kernel<<<dim3(128, 8), blk, 0, stream_>>>(wA, wB, vA, vB, aA, aB, gA, gB,
                                                   wAB, wBB, vAB, vBB, aAB, aBB, gAB, gBB);
    mix_kernel<<<(NTOK * Dx / 4) / 256, blk, 0, stream_>>>(x, x_r, x_w, x_k, x_v, x_a, x_g,
                                                           XR, XW, XK, XV, XA, XG);
    // big projections (B = f32 weights, converted in staging)
    gemm_nt<128, 0, false, false, true><<<dim3(64, 8), blk, 0, stream_>>>(XR, Wr, nullptr, Rbuf, NTOK, 1024, 1024);
    gemm_nt<128, 0, false, false, true><<<dim3(64, 8), blk, 0, stream_>>>(XK, Wk, nullptr, Kbuf, NTOK, 1024, 1024);
    gemm_nt<128, 0, false, false, true><<<dim3(64, 8), blk, 0, stream_>>>(XV, Wv, nullptr, Vbuf, NTOK, 1024, 1024);
    // lora stage 1
    gemm_nt<64, 2, false, false, false><<<dim3(64, 1), blk, 0, stream_>>>(XW, wAB, nullptr, HW, NTOK, 64, 1024);
    gemm_nt<64, 0, false, false, false><<<dim3(64, 1), blk, 0, stream_>>>(XA, aAB, nullptr, HA, NTOK, 64, 1024);
    gemm_nt<32, 0, false, false, false><<<dim3(64, 1), blk, 0, stream_>>>(XV, vAB, nullptr, HV, NTOK, 32, 1024);
    gemm_nt<128, 1, false, false, false><<<dim3(64, 1), blk, 0, stream_>>>(XG, gAB, nullptr, HG, NTOK, 128, 1024);
    // lora stage 2
    gemm_nt<128, 3, true,  false, false><<<dim3(64, 8), blk, 0, stream_>>>(HW, wBB, wb, Wdec16, NTOK, 1024, 64);
    gemm_nt<128, 1, true,  false, false><<<dim3(64, 8), blk, 0, stream_>>>(HA, aBB, ab, ICLR, NTOK, 1024, 64);
    gemm_nt<128, 1, true,  false, false><<<dim3(64, 8), blk, 0, stream_>>>(HV, vBB, vb, VVb, NTOK, 1024, 32);
    gemm_nt<128, 0, false, false, false><<<dim3(64, 8), blk, 0, stream_>>>(HG, gBB, nullptr, GATE, NTOK, 1024, 128);

    prep_pack_kernel<<<(NTOK * Hx) / 4, blk, 0, stream_>>>(Kbuf, Vbuf, Rbuf, Wdec16, ICLR, VVb,
                                                           vfirst, k_k, k_a, STREAM);
    scan_kernel<<<128, blk, 0, stream_>>>(STREAM, Yb);
    gnorm_kernel<<<(NTOK * Hx) / 4, blk, 0, stream_>>>(Yb, Rbuf, Kbuf, Vbuf, r_k, gnw, gnb, GATE);
    gemm_nt<128, 0, false, true, true><<<dim3(64, 8), blk, 0, stream_>>>(GATE, Wo, nullptr, d_out, NTOK, 1024, 1024);
}